// Round 8
// baseline (747.653 us; speedup 1.0000x reference)
//
#include <hip/hip_runtime.h>
#include <cstdint>

#define R_TOT 16384
#define T_NT  2048
#define DD    128
#define HH    512
#define MC_   20
#define NBLK  1024           // R_TOT / 16 rows per block
#define NSC   128            // 16-col steps total
#define SPW   32             // steps per wave (NSC / 4 waves)

// Output layout (floats)
#define MASK_OFF 0
#define LOGP_OFF 16384
#define WORD_OFF 32768
#define CHAR_OFF 49152
#define EMB_OFF  376832          // 49152 + 16384*20
#define LOSS_OFF 2473984         // 376832 + 16384*128

// ws layout (float slots)
#define X_OFF     0              // x f32 [16384][128]
#define HDN_OFF   2097152        // hdn f32 [16384][512]
#define HDNB_OFF  10485760       // hdn bf16 ushort[16384*512]
#define WT_OFF    14680064       // wtgt f32 [2048][128]; reused as entP/cntP after k1b
#define WTT4_OFF  14942208       // wtgtT4 ushort[128][8][64][8]   (524288)
#define W2T_OFF   15204352       // W2Tf f32 [2048][512]
#define W2P_OFF   16252928       // W2p ushort[128][16][512]       (1048576)

typedef __attribute__((ext_vector_type(8))) short short8v;
typedef __attribute__((ext_vector_type(4))) float f32x4;
typedef unsigned short ushort_t;

__device__ __forceinline__ ushort_t f2bf(float f) {
    union { float f; unsigned int u; } v; v.f = f;
    unsigned int r = v.u + 0x7FFFu + ((v.u >> 16) & 1u);
    return (ushort_t)(r >> 16);
}

// ---------------- K1: gather embeddings ----------------
__global__ __launch_bounds__(256) void k1_gather(
    const int* __restrict__ inp_word, const int* __restrict__ tgt_ids,
    const float* __restrict__ W, float* __restrict__ x, float* __restrict__ wtgt)
{
    int row = blockIdx.x * 2 + (threadIdx.x >> 7);
    int d = threadIdx.x & 127;
    if (row < R_TOT) {
        int wsrc = inp_word[row];
        x[(size_t)row * DD + d] = W[(size_t)wsrc * DD + d];
    } else {
        int rr = row - R_TOT;
        if (rr < T_NT) {
            int wsrc = tgt_ids[rr];
            wtgt[(size_t)rr * DD + d] = W[(size_t)wsrc * DD + d];
        }
    }
}

// ---------------- K1b: wtgt -> wtgtT4 PV B-fragment pack ----------------
// wtgtT4[(sc*8+df)*512 + lane*8 + j] = j<4 ? bf16(wtgt[sc*16+(lane>>4)*4+j][df*16+(lane&15)]) : 0
__global__ __launch_bounds__(256) void k1b_wtgtT4(
    const float* __restrict__ wtgt, ushort_t* __restrict__ wtgtT4)
{
    const int js = blockIdx.x, t = threadIdx.x;
    #pragma unroll
    for (int i = 0; i < 4; ++i) {
        int s = i * 256 + t;
        int cs = s >> 9, rem = s & 511;
        int df = rem >> 6, lane = rem & 63;
        int lrow = lane & 15, kg = lane >> 4;
        ushort_t* dst = wtgtT4 + (size_t)(((js * 2 + cs) * 8 + df) * 512 + lane * 8);
        #pragma unroll
        for (int j = 0; j < 8; ++j) {
            dst[j] = (j < 4)
                ? f2bf(wtgt[(size_t)(js * 32 + cs * 16 + kg * 4 + j) * DD + df * 16 + lrow])
                : (ushort_t)0;
        }
    }
}

// ---------------- K0: W2 [512][2048] -> W2Tf f32 + W2p fragment pack ----------------
// W2p[sc][ks][lane*8+j] = bf16(W2[ks*32 + (lane>>4)*8 + j][sc*16 + (lane&15)])
__global__ __launch_bounds__(256) void k0_w2t(
    const float* __restrict__ W2, float* __restrict__ W2Tf, ushort_t* __restrict__ W2p)
{
    __shared__ float tile[32][33];
    const int jc = blockIdx.x, jk = blockIdx.y;
    const int cb = jc * 32, kb = jk * 32;
    const int lx = threadIdx.x & 31, ly = threadIdx.x >> 5;
    #pragma unroll
    for (int i = 0; i < 32; i += 8)
        tile[ly + i][lx] = W2[(size_t)(kb + ly + i) * T_NT + cb + lx];
    __syncthreads();
    #pragma unroll
    for (int i = 0; i < 32; i += 8)
        W2Tf[(size_t)(cb + ly + i) * HH + kb + lx] = tile[lx][ly + i];
    if (threadIdx.x < 128) {
        int cs = threadIdx.x >> 6, lane = threadIdx.x & 63;
        int lrow = lane & 15, kgrp = lane >> 4;
        ushort_t* dst = W2p + (size_t)((cb / 16 + cs) * 16 + jk) * 512 + lane * 8;
        #pragma unroll
        for (int j = 0; j < 8; ++j)
            dst[j] = f2bf(tile[kgrp * 8 + j][cs * 16 + lrow]);
    }
}

// ---------------- K2: hdn = relu(x @ W1 + b1), fp32 + bf16 outputs ----------------
__global__ __launch_bounds__(256) void k2_hdn(
    const float* __restrict__ x, const float* __restrict__ W1,
    const float* __restrict__ b1, float* __restrict__ hdn, ushort_t* __restrict__ hdnB)
{
    __shared__ float As[16][64];
    __shared__ float Bs[16][64];
    const int t = threadIdx.x;
    const int bm = blockIdx.x * 64;
    const int bn = blockIdx.y * 64;
    const int tx = t & 15, ty = t >> 4;
    float acc[4][4] = {};
    for (int k0 = 0; k0 < DD; k0 += 16) {
        {
            int m = t >> 2, kq = t & 3;
            float4 v = *(const float4*)(x + (size_t)(bm + m) * DD + k0 + kq * 4);
            As[kq * 4 + 0][m] = v.x; As[kq * 4 + 1][m] = v.y;
            As[kq * 4 + 2][m] = v.z; As[kq * 4 + 3][m] = v.w;
        }
        {
            int k = t >> 4, nq = t & 15;
            *(float4*)(&Bs[k][nq * 4]) =
                *(const float4*)(W1 + (size_t)(k0 + k) * HH + bn + nq * 4);
        }
        __syncthreads();
        #pragma unroll
        for (int k = 0; k < 16; ++k) {
            float a[4], b[4];
            #pragma unroll
            for (int i = 0; i < 4; i++) a[i] = As[k][ty * 4 + i];
            #pragma unroll
            for (int j = 0; j < 4; j++) b[j] = Bs[k][tx * 4 + j];
            #pragma unroll
            for (int i = 0; i < 4; i++)
                #pragma unroll
                for (int j = 0; j < 4; j++)
                    acc[i][j] = fmaf(a[i], b[j], acc[i][j]);
        }
        __syncthreads();
    }
    #pragma unroll
    for (int i = 0; i < 4; i++) {
        int m = bm + ty * 4 + i;
        int n = bn + tx * 4;
        float4 v;
        v.x = fmaxf(acc[i][0] + b1[n + 0], 0.f);
        v.y = fmaxf(acc[i][1] + b1[n + 1], 0.f);
        v.z = fmaxf(acc[i][2] + b1[n + 2], 0.f);
        v.w = fmaxf(acc[i][3] + b1[n + 3], 0.f);
        *(float4*)(hdn + (size_t)m * HH + n) = v;
        ushort4 hb;
        hb.x = f2bf(v.x); hb.y = f2bf(v.y); hb.z = f2bf(v.z); hb.w = f2bf(v.w);
        *(ushort4*)(hdnB + (size_t)m * HH + n) = hb;
    }
}

// ---------------- K3: 16 rows/block, 4 independent col-split waves, no in-loop barriers ----------------
// grid 1024 x 256 threads -> 4 blocks/CU = 16 waves/CU = 4/SIMD.
__global__ __launch_bounds__(256, 4) void k3_fused(
    const ushort_t* __restrict__ hdnB, const float* __restrict__ hdn,
    const ushort_t* __restrict__ W2p, const float* __restrict__ W2Tf,
    const float* __restrict__ b2, const float* __restrict__ gumbel,
    const int* __restrict__ inp_word, const int* __restrict__ keyword_table,
    const int* __restrict__ tgt_ids, const int* __restrict__ lut,
    const float* __restrict__ x, const ushort_t* __restrict__ wtgtT4,
    float* __restrict__ out, float* __restrict__ entP, float* __restrict__ cntP)
{
    __shared__ float bigS[6144];       // 24KB: A-pack (16KB) then PV-merge scratch
    __shared__ float pS[4][16 * 20];   // per-wave P transpose tiles
    __shared__ float statP[4][16][8];
    __shared__ int   candS[16 * 2];
    __shared__ int   mskS[16];

    const int t = threadIdx.x;
    const int wid = t >> 6, lane = t & 63;
    const int lrow = lane & 15, kgrp = lane >> 4;
    const int row0 = blockIdx.x * 16;

    ushort_t* aP = (ushort_t*)bigS;    // [ks 0..15][lane][8]

    // ---- A-pack: hdnB rows -> fragment-major LDS ----
    #pragma unroll
    for (int i = 0; i < 4; ++i) {
        int gid = i * 256 + t;          // 1024 granules
        int ks = gid >> 6, l2 = gid & 63;
        int lr = l2 & 15, kg = l2 >> 4;
        uint4 v = *(const uint4*)(hdnB + (size_t)(row0 + lr) * HH + ks * 32 + kg * 8);
        *(uint4*)(aP + gid * 8) = v;
    }
    __syncthreads();

    const ushort_t* aLane = aP + lane * 8;   // + ks*512 (imm ks*1024B)

    // ---- per-wave pointers ----
    const int base_sc = ((blockIdx.x & 31) * 4 + wid) & 127;
    const float* gq[4];
    #pragma unroll
    for (int q = 0; q < 4; ++q)
        gq[q] = gumbel + (size_t)(row0 + kgrp * 4 + q) * T_NT + lrow;
    const float* b2p = b2 + lrow;
    float* pw = &pS[wid][0];

    float m_[4], sE_[4], sEl_[4], s2_[4], a1_[4], a2_[4];
    int i1_[4], i2_[4];
    #pragma unroll
    for (int q = 0; q < 4; ++q) {
        m_[q] = -1e30f; sE_[q] = 0.f; sEl_[q] = 0.f; s2_[q] = 0.f;
        a1_[q] = -1e30f; a2_[q] = -1e30f; i1_[q] = 0; i2_[q] = 0;
    }
    f32x4 accpv[8];
    #pragma unroll
    for (int df = 0; df < 8; ++df) accpv[df] = (f32x4){0.f, 0.f, 0.f, 0.f};

    // gumbel prefetch for first step
    float gc0 = gq[0][base_sc * 16], gc1 = gq[1][base_sc * 16];
    float gc2 = gq[2][base_sc * 16], gc3 = gq[3][base_sc * 16];

    int scc = base_sc;
    for (int s = 0; s < SPW; ++s) {
        const int scn = (scc + 4) & 127;
        float b2v = b2p[scc * 16];

        // S tile: 16 B L2-loads + 16 A ds_reads + 16 MFMA (4 chains)
        const ushort_t* bp = W2p + (size_t)scc * 8192 + lane * 8;
        f32x4 c[4];
        #pragma unroll
        for (int j = 0; j < 4; ++j) c[j] = (f32x4){0.f, 0.f, 0.f, 0.f};
        #pragma unroll
        for (int ks = 0; ks < 16; ++ks) {
            short8v a = *(const short8v*)(aLane + ks * 512);
            short8v b = *(const short8v*)(bp + ks * 512);
            c[ks & 3] = __builtin_amdgcn_mfma_f32_16x16x32_bf16(a, b, c[ks & 3], 0, 0, 0);
        }
        f32x4 acc = (c[0] + c[1]) + (c[2] + c[3]);

        // prefetch next-step gumbel
        float gn0 = gq[0][scn * 16], gn1 = gq[1][scn * 16];
        float gn2 = gq[2][scn * 16], gn3 = gq[3][scn * 16];

        // PV B-frags for this step
        const ushort_t* vp = wtgtT4 + (size_t)scc * 4096 + lane * 8;
        short8v bvf[8];
        #pragma unroll
        for (int df = 0; df < 8; ++df) bvf[df] = *(const short8v*)(vp + df * 512);

        // stats + top2 + P write
        const int colv = scc * 16 + lrow;
        float g4[4] = {gc0, gc1, gc2, gc3};
        #pragma unroll
        for (int q = 0; q < 4; ++q) {
            float l = acc[q] + b2v;
            m_[q] = fmaxf(m_[q], l);
            float e1 = __expf(l);
            sE_[q] += e1; sEl_[q] = fmaf(e1, l, sEl_[q]);
            float a = l + g4[q];
            float p = __expf(2.0f * a);
            s2_[q] += p;
            if (a > a1_[q]) { a2_[q] = a1_[q]; i2_[q] = i1_[q]; a1_[q] = a; i1_[q] = colv; }
            else if (a > a2_[q]) { a2_[q] = a; i2_[q] = colv; }
            pw[(kgrp * 4 + q) * 20 + lrow] = p;
        }

        // PV: transpose-read own P (same-wave), K=16 zero-padded MFMA
        {
            float4 p4 = *(const float4*)(pw + lrow * 20 + kgrp * 4);
            short8v pav;
            pav[0] = (short)f2bf(p4.x); pav[1] = (short)f2bf(p4.y);
            pav[2] = (short)f2bf(p4.z); pav[3] = (short)f2bf(p4.w);
            pav[4] = 0; pav[5] = 0; pav[6] = 0; pav[7] = 0;
            #pragma unroll
            for (int df = 0; df < 8; ++df)
                accpv[df] = __builtin_amdgcn_mfma_f32_16x16x32_bf16(pav, bvf[df], accpv[df], 0, 0, 0);
        }

        gc0 = gn0; gc1 = gn1; gc2 = gn2; gc3 = gn3;
        scc = scn;
    }

    // ---- in-wave reduction over the 16 lrow lanes ----
    #pragma unroll
    for (int q = 0; q < 4; ++q) {
        #pragma unroll
        for (int mk = 1; mk < 16; mk <<= 1) {
            m_[q] = fmaxf(m_[q], __shfl_xor(m_[q], mk));
            sE_[q] += __shfl_xor(sE_[q], mk);
            sEl_[q] += __shfl_xor(sEl_[q], mk);
            s2_[q] += __shfl_xor(s2_[q], mk);
            float ob1 = __shfl_xor(a1_[q], mk); int oj1 = __shfl_xor(i1_[q], mk);
            float ob2 = __shfl_xor(a2_[q], mk); int oj2 = __shfl_xor(i2_[q], mk);
            if (ob1 > a1_[q] || (ob1 == a1_[q] && oj1 < i1_[q])) {
                if (a1_[q] > ob2 || (a1_[q] == ob2 && i1_[q] < oj2)) { a2_[q] = a1_[q]; i2_[q] = i1_[q]; }
                else { a2_[q] = ob2; i2_[q] = oj2; }
                a1_[q] = ob1; i1_[q] = oj1;
            } else {
                if (ob1 > a2_[q]) { a2_[q] = ob1; i2_[q] = oj1; }
            }
        }
    }

    __syncthreads();   // all waves done with aP; scratch reuse safe

    // ---- publish partials ----
    if (lrow == 0) {
        #pragma unroll
        for (int q = 0; q < 4; ++q) {
            float* st = &statP[wid][kgrp * 4 + q][0];
            st[0] = m_[q]; st[1] = sE_[q]; st[2] = sEl_[q]; st[3] = s2_[q];
            st[4] = a1_[q]; st[5] = __int_as_float(i1_[q]);
            st[6] = a2_[q]; st[7] = __int_as_float(i2_[q]);
        }
    }
    if (wid >= 1) {
        float* scr = bigS + (wid - 1) * 2048;
        #pragma unroll
        for (int df = 0; df < 8; ++df)
            #pragma unroll
            for (int q = 0; q < 4; ++q)
                scr[(kgrp * 4 + q) * 128 + df * 16 + lrow] = accpv[df][q];
    }
    __syncthreads();

    // ---- wave 0: merge + scalar outputs + x_emb ----
    if (wid == 0) {
        float invs2_[4]; int msk_[4];
        float es = 0.f; int cs = 0;
        #pragma unroll
        for (int q = 0; q < 4; ++q) {
            int r = kgrp * 4 + q;
            float M = m_[q], SE = sE_[q], SEL = sEl_[q], S2 = s2_[q];
            float A1 = a1_[q], A2 = a2_[q]; int I1 = i1_[q], I2 = i2_[q];
            #pragma unroll
            for (int w = 1; w < 4; ++w) {
                const float* st = &statP[w][r][0];
                float ob1 = st[4]; int oj1 = __float_as_int(st[5]);
                float ob2 = st[6]; int oj2 = __float_as_int(st[7]);
                M = fmaxf(M, st[0]); SE += st[1]; SEL += st[2]; S2 += st[3];
                if (ob1 > A1 || (ob1 == A1 && oj1 < I1)) {
                    if (A1 > ob2 || (A1 == ob2 && I1 < oj2)) { A2 = A1; I2 = I1; }
                    else { A2 = ob2; I2 = oj2; }
                    A1 = ob1; I1 = oj1;
                } else {
                    if (ob1 > A2) { A2 = ob1; I2 = oj1; }
                }
            }
            invs2_[q] = 1.0f / S2;
            int grow = row0 + r;
            int w_in = inp_word[grow];
            int msk = keyword_table[w_in] != 0;
            msk_[q] = msk;
            float entq = msk ? (__logf(SE) - SEL / SE) : 0.0f;
            es += entq; cs += msk;
            if (lrow == 0) {
                out[MASK_OFF + grow] = msk ? 1.0f : 0.0f;
                out[LOGP_OFF + grow] = msk ? M : 0.0f;
                mskS[r] = msk;
                candS[r * 2 + 0] = I1;
                candS[r * 2 + 1] = I2;
            }
        }
        // loss partials (sum over the 4 kgrp groups)
        {
            float e0 = __shfl(es, 0), e16 = __shfl(es, 16), e32 = __shfl(es, 32), e48 = __shfl(es, 48);
            int c0 = __shfl(cs, 0), c16 = __shfl(cs, 16), c32 = __shfl(cs, 32), c48 = __shfl(cs, 48);
            if (lane == 0) {
                entP[blockIdx.x] = e0 + e16 + e32 + e48;
                cntP[blockIdx.x] = (float)(c0 + c16 + c32 + c48);
            }
        }
        // merge PV partials + store x_emb
        #pragma unroll
        for (int df = 0; df < 8; ++df) {
            #pragma unroll
            for (int q = 0; q < 4; ++q) {
                int r = kgrp * 4 + q;
                float v = accpv[df][q]
                        + bigS[0 * 2048 + r * 128 + df * 16 + lrow]
                        + bigS[1 * 2048 + r * 128 + df * 16 + lrow]
                        + bigS[2 * 2048 + r * 128 + df * 16 + lrow];
                int grow = row0 + r;
                int d = df * 16 + lrow;
                float val = v * invs2_[q];
                if (!msk_[q]) val = x[(size_t)grow * DD + d];
                out[EMB_OFF + (size_t)grow * DD + d] = val;
            }
        }
    }
    __syncthreads();

    // ---- repair + word/char: wave wid handles rows wid, wid+4, wid+8, wid+12 ----
    for (int rr = wid; rr < 16; rr += 4) {
        int grow = row0 + rr;
        int i1 = candS[rr * 2 + 0], i2 = candS[rr * 2 + 1];
        int mskr = mskS[rr];
        const float* hrow = hdn + (size_t)grow * HH;
        float4 h0 = *(const float4*)(hrow + lane * 8);
        float4 h1 = *(const float4*)(hrow + lane * 8 + 4);
        float v1, v2;
        {
            const float* wrow = W2Tf + (size_t)i1 * HH;
            float4 w0 = *(const float4*)(wrow + lane * 8);
            float4 w1 = *(const float4*)(wrow + lane * 8 + 4);
            float sdot = h0.x*w0.x + h0.y*w0.y + h0.z*w0.z + h0.w*w0.w
                       + h1.x*w1.x + h1.y*w1.y + h1.z*w1.z + h1.w*w1.w;
            #pragma unroll
            for (int mk = 1; mk < 64; mk <<= 1) sdot += __shfl_xor(sdot, mk);
            v1 = sdot + b2[i1] + gumbel[(size_t)grow * T_NT + i1];
        }
        {
            const float* wrow = W2Tf + (size_t)i2 * HH;
            float4 w0 = *(const float4*)(wrow + lane * 8);
            float4 w1 = *(const float4*)(wrow + lane * 8 + 4);
            float sdot = h0.x*w0.x + h0.y*w0.y + h0.z*w0.z + h0.w*w0.w
                       + h1.x*w1.x + h1.y*w1.y + h1.z*w1.z + h1.w*w1.w;
            #pragma unroll
            for (int mk = 1; mk < 64; mk <<= 1) sdot += __shfl_xor(sdot, mk);
            v2 = sdot + b2[i2] + gumbel[(size_t)grow * T_NT + i2];
        }
        int ibest = (v2 > v1 || (v2 == v1 && i2 < i1)) ? i2 : i1;
        int word = mskr ? tgt_ids[ibest] : inp_word[grow];
        if (lane == 0) out[WORD_OFF + grow] = (float)word;
        if (lane < MC_)
            out[CHAR_OFF + (size_t)grow * MC_ + lane] = (float)lut[(size_t)word * MC_ + lane];
    }
}

// ---------------- K4: final loss reduction ----------------
__global__ __launch_bounds__(256) void k4_loss(
    const float* __restrict__ entP, const float* __restrict__ cntP, float* __restrict__ out)
{
    __shared__ float sE[256], sC[256];
    int t = threadIdx.x;
    float e = 0.f, c = 0.f;
    for (int i = t; i < NBLK; i += 256) { e += entP[i]; c += cntP[i]; }
    sE[t] = e; sC[t] = c;
    __syncthreads();
    for (int s = 128; s > 0; s >>= 1) {
        if (t < s) { sE[t] += sE[t + s]; sC[t] += sC[t + s]; }
        __syncthreads();
    }
    if (t == 0) {
        float ns = fmaxf(sC[0], 1.0f);
        out[LOSS_OFF] = 0.03f * sE[0] / ns;
    }
}

// ---------------- launch ----------------
extern "C" void kernel_launch(void* const* d_in, const int* in_sizes, int n_in,
                              void* d_out, int out_size, void* d_ws, size_t ws_size,
                              hipStream_t stream) {
    const int* inp_word = (const int*)d_in[0];
    const int* keyword_table = (const int*)d_in[3];
    const int* tgt_ids = (const int*)d_in[4];
    const int* lut = (const int*)d_in[5];
    const float* gumbel = (const float*)d_in[6];
    const float* W = (const float*)d_in[7];
    const float* W1 = (const float*)d_in[8];
    const float* b1 = (const float*)d_in[9];
    const float* W2 = (const float*)d_in[10];
    const float* b2 = (const float*)d_in[11];
    float* out = (float*)d_out;

    float* wsf = (float*)d_ws;
    float* x = wsf + X_OFF;
    float* hdn = wsf + HDN_OFF;
    ushort_t* hdnB = (ushort_t*)(wsf + HDNB_OFF);
    float* wtgt = wsf + WT_OFF;
    ushort_t* wtgtT4 = (ushort_t*)(wsf + WTT4_OFF);
    float* W2Tf = wsf + W2T_OFF;
    ushort_t* W2p = (ushort_t*)(wsf + W2P_OFF);
    float* entP = wsf + WT_OFF;          // wtgt region dead after k1b
    float* cntP = wsf + WT_OFF + 1024;

    k1_gather<<<(R_TOT + T_NT) / 2, 256, 0, stream>>>(inp_word, tgt_ids, W, x, wtgt);
    k1b_wtgtT4<<<64, 256, 0, stream>>>(wtgt, wtgtT4);
    k0_w2t<<<dim3(T_NT / 32, HH / 32), 256, 0, stream>>>(W2, W2Tf, W2p);
    k2_hdn<<<dim3(R_TOT / 64, HH / 64), 256, 0, stream>>>(x, W1, b1, hdn, hdnB);
    k3_fused<<<NBLK, 256, 0, stream>>>(hdnB, hdn, W2p, W2Tf, b2, gumbel,
                                       inp_word, keyword_table, tgt_ids, lut,
                                       x, wtgtT4, out, entP, cntP);
    k4_loss<<<1, 256, 0, stream>>>(entP, cntP, out);
}

// Round 9
// 704.076 us; speedup vs baseline: 1.0619x; 1.0619x over previous
//
#include <hip/hip_runtime.h>
#include <cstdint>

#define R_TOT 16384
#define T_NT  2048
#define DD    128
#define HH    512
#define MC_   20
#define NBLK  1024           // R_TOT / 16 rows per block
#define NSC   128            // 16-col steps total
#define SPW   32             // steps per wave (NSC / 4 waves)

// Output layout (floats)
#define MASK_OFF 0
#define LOGP_OFF 16384
#define WORD_OFF 32768
#define CHAR_OFF 49152
#define EMB_OFF  376832          // 49152 + 16384*20
#define LOSS_OFF 2473984         // 376832 + 16384*128

// ws layout (float slots)
#define X_OFF     0              // x f32 [16384][128]
#define HDN_OFF   2097152        // hdn f32 [16384][512]
#define HDNB_OFF  10485760       // hdn bf16 ushort[16384*512]
#define WT_OFF    14680064       // wtgt f32 [2048][128]; reused as entP/cntP after k1b
#define WTT4_OFF  14942208       // wtgtT4 ushort[128][8][64][8]   (524288)
#define W2T_OFF   15204352       // W2Tf f32 [2048][512]
#define W2P_OFF   16252928       // W2p ushort[128][16][512]       (1048576)

typedef __attribute__((ext_vector_type(8))) short short8v;
typedef __attribute__((ext_vector_type(4))) float f32x4;
typedef unsigned short ushort_t;

__device__ __forceinline__ ushort_t f2bf(float f) {
    union { float f; unsigned int u; } v; v.f = f;
    unsigned int r = v.u + 0x7FFFu + ((v.u >> 16) & 1u);
    return (ushort_t)(r >> 16);
}

// ---------------- K1: gather embeddings ----------------
__global__ __launch_bounds__(256) void k1_gather(
    const int* __restrict__ inp_word, const int* __restrict__ tgt_ids,
    const float* __restrict__ W, float* __restrict__ x, float* __restrict__ wtgt)
{
    int row = blockIdx.x * 2 + (threadIdx.x >> 7);
    int d = threadIdx.x & 127;
    if (row < R_TOT) {
        int wsrc = inp_word[row];
        x[(size_t)row * DD + d] = W[(size_t)wsrc * DD + d];
    } else {
        int rr = row - R_TOT;
        if (rr < T_NT) {
            int wsrc = tgt_ids[rr];
            wtgt[(size_t)rr * DD + d] = W[(size_t)wsrc * DD + d];
        }
    }
}

// ---------------- K1b: wtgt -> wtgtT4 PV B-fragment pack ----------------
// wtgtT4[(sc*8+df)*512 + lane*8 + j] = j<4 ? bf16(wtgt[sc*16+(lane>>4)*4+j][df*16+(lane&15)]) : 0
__global__ __launch_bounds__(256) void k1b_wtgtT4(
    const float* __restrict__ wtgt, ushort_t* __restrict__ wtgtT4)
{
    const int js = blockIdx.x, t = threadIdx.x;
    #pragma unroll
    for (int i = 0; i < 4; ++i) {
        int s = i * 256 + t;
        int cs = s >> 9, rem = s & 511;
        int df = rem >> 6, lane = rem & 63;
        int lrow = lane & 15, kg = lane >> 4;
        ushort_t* dst = wtgtT4 + (size_t)(((js * 2 + cs) * 8 + df) * 512 + lane * 8);
        #pragma unroll
        for (int j = 0; j < 8; ++j) {
            dst[j] = (j < 4)
                ? f2bf(wtgt[(size_t)(js * 32 + cs * 16 + kg * 4 + j) * DD + df * 16 + lrow])
                : (ushort_t)0;
        }
    }
}

// ---------------- K0: W2 [512][2048] -> W2Tf f32 + W2p fragment pack ----------------
// W2p[sc][ks][lane*8+j] = bf16(W2[ks*32 + (lane>>4)*8 + j][sc*16 + (lane&15)])
__global__ __launch_bounds__(256) void k0_w2t(
    const float* __restrict__ W2, float* __restrict__ W2Tf, ushort_t* __restrict__ W2p)
{
    __shared__ float tile[32][33];
    const int jc = blockIdx.x, jk = blockIdx.y;
    const int cb = jc * 32, kb = jk * 32;
    const int lx = threadIdx.x & 31, ly = threadIdx.x >> 5;
    #pragma unroll
    for (int i = 0; i < 32; i += 8)
        tile[ly + i][lx] = W2[(size_t)(kb + ly + i) * T_NT + cb + lx];
    __syncthreads();
    #pragma unroll
    for (int i = 0; i < 32; i += 8)
        W2Tf[(size_t)(cb + ly + i) * HH + kb + lx] = tile[lx][ly + i];
    if (threadIdx.x < 128) {
        int cs = threadIdx.x >> 6, lane = threadIdx.x & 63;
        int lrow = lane & 15, kgrp = lane >> 4;
        ushort_t* dst = W2p + (size_t)((cb / 16 + cs) * 16 + jk) * 512 + lane * 8;
        #pragma unroll
        for (int j = 0; j < 8; ++j)
            dst[j] = f2bf(tile[kgrp * 8 + j][cs * 16 + lrow]);
    }
}

// ---------------- K2: hdn = relu(x @ W1 + b1), fp32 + bf16 outputs ----------------
__global__ __launch_bounds__(256) void k2_hdn(
    const float* __restrict__ x, const float* __restrict__ W1,
    const float* __restrict__ b1, float* __restrict__ hdn, ushort_t* __restrict__ hdnB)
{
    __shared__ float As[16][64];
    __shared__ float Bs[16][64];
    const int t = threadIdx.x;
    const int bm = blockIdx.x * 64;
    const int bn = blockIdx.y * 64;
    const int tx = t & 15, ty = t >> 4;
    float acc[4][4] = {};
    for (int k0 = 0; k0 < DD; k0 += 16) {
        {
            int m = t >> 2, kq = t & 3;
            float4 v = *(const float4*)(x + (size_t)(bm + m) * DD + k0 + kq * 4);
            As[kq * 4 + 0][m] = v.x; As[kq * 4 + 1][m] = v.y;
            As[kq * 4 + 2][m] = v.z; As[kq * 4 + 3][m] = v.w;
        }
        {
            int k = t >> 4, nq = t & 15;
            *(float4*)(&Bs[k][nq * 4]) =
                *(const float4*)(W1 + (size_t)(k0 + k) * HH + bn + nq * 4);
        }
        __syncthreads();
        #pragma unroll
        for (int k = 0; k < 16; ++k) {
            float a[4], b[4];
            #pragma unroll
            for (int i = 0; i < 4; i++) a[i] = As[k][ty * 4 + i];
            #pragma unroll
            for (int j = 0; j < 4; j++) b[j] = Bs[k][tx * 4 + j];
            #pragma unroll
            for (int i = 0; i < 4; i++)
                #pragma unroll
                for (int j = 0; j < 4; j++)
                    acc[i][j] = fmaf(a[i], b[j], acc[i][j]);
        }
        __syncthreads();
    }
    #pragma unroll
    for (int i = 0; i < 4; i++) {
        int m = bm + ty * 4 + i;
        int n = bn + tx * 4;
        float4 v;
        v.x = fmaxf(acc[i][0] + b1[n + 0], 0.f);
        v.y = fmaxf(acc[i][1] + b1[n + 1], 0.f);
        v.z = fmaxf(acc[i][2] + b1[n + 2], 0.f);
        v.w = fmaxf(acc[i][3] + b1[n + 3], 0.f);
        *(float4*)(hdn + (size_t)m * HH + n) = v;
        ushort4 hb;
        hb.x = f2bf(v.x); hb.y = f2bf(v.y); hb.z = f2bf(v.z); hb.w = f2bf(v.w);
        *(ushort4*)(hdnB + (size_t)m * HH + n) = hb;
    }
}

// ---------------- K3: 16 rows/block, 4 independent col-split waves, no in-loop barriers ----------------
// grid 1024 x 256 threads; launch_bounds(256,3) -> ~170 VGPR, 3 blocks/CU = 12 waves/CU.
__global__ __launch_bounds__(256, 3) void k3_fused(
    const ushort_t* __restrict__ hdnB, const float* __restrict__ hdn,
    const ushort_t* __restrict__ W2p, const float* __restrict__ W2Tf,
    const float* __restrict__ b2, const float* __restrict__ gumbel,
    const int* __restrict__ inp_word, const int* __restrict__ keyword_table,
    const int* __restrict__ tgt_ids, const int* __restrict__ lut,
    const float* __restrict__ x, const ushort_t* __restrict__ wtgtT4,
    float* __restrict__ out, float* __restrict__ entP, float* __restrict__ cntP)
{
    __shared__ float bigS[6144];       // 24KB: A-pack (16KB) then PV-merge scratch
    __shared__ float pS[4][16 * 20];   // per-wave P transpose tiles
    __shared__ float statP[4][16][8];
    __shared__ int   candS[16 * 2];
    __shared__ int   mskS[16];

    const int t = threadIdx.x;
    const int wid = t >> 6, lane = t & 63;
    const int lrow = lane & 15, kgrp = lane >> 4;
    const int row0 = blockIdx.x * 16;

    ushort_t* aP = (ushort_t*)bigS;    // [ks 0..15][lane][8]

    // ---- A-pack: hdnB rows -> fragment-major LDS ----
    #pragma unroll
    for (int i = 0; i < 4; ++i) {
        int gid = i * 256 + t;          // 1024 granules
        int ks = gid >> 6, l2 = gid & 63;
        int lr = l2 & 15, kg = l2 >> 4;
        uint4 v = *(const uint4*)(hdnB + (size_t)(row0 + lr) * HH + ks * 32 + kg * 8);
        *(uint4*)(aP + gid * 8) = v;
    }
    __syncthreads();

    const ushort_t* aLane = aP + lane * 8;   // + ks*512 (imm ks*1024B)

    // ---- per-wave pointers ----
    const int base_sc = ((blockIdx.x & 31) * 4 + wid) & 127;
    const float* gq[4];
    #pragma unroll
    for (int q = 0; q < 4; ++q)
        gq[q] = gumbel + (size_t)(row0 + kgrp * 4 + q) * T_NT + lrow;
    const float* b2p = b2 + lrow;
    float* pw = &pS[wid][0];

    float m_[4], sE_[4], sEl_[4], s2_[4], a1_[4], a2_[4];
    int i1_[4], i2_[4];
    #pragma unroll
    for (int q = 0; q < 4; ++q) {
        m_[q] = -1e30f; sE_[q] = 0.f; sEl_[q] = 0.f; s2_[q] = 0.f;
        a1_[q] = -1e30f; a2_[q] = -1e30f; i1_[q] = 0; i2_[q] = 0;
    }
    f32x4 accpv[8];
    #pragma unroll
    for (int df = 0; df < 8; ++df) accpv[df] = (f32x4){0.f, 0.f, 0.f, 0.f};

    // gumbel prefetch for first step
    float gc0 = gq[0][base_sc * 16], gc1 = gq[1][base_sc * 16];
    float gc2 = gq[2][base_sc * 16], gc3 = gq[3][base_sc * 16];

    int scc = base_sc;
    for (int s = 0; s < SPW; ++s) {
        const int scn = (scc + 4) & 127;
        float b2v = b2p[scc * 16];

        // S tile: 16 B L2-loads + 16 A ds_reads + 16 MFMA (4 chains)
        const ushort_t* bp = W2p + (size_t)scc * 8192 + lane * 8;
        f32x4 c[4];
        #pragma unroll
        for (int j = 0; j < 4; ++j) c[j] = (f32x4){0.f, 0.f, 0.f, 0.f};
        #pragma unroll
        for (int ks = 0; ks < 16; ++ks) {
            short8v a = *(const short8v*)(aLane + ks * 512);
            short8v b = *(const short8v*)(bp + ks * 512);
            c[ks & 3] = __builtin_amdgcn_mfma_f32_16x16x32_bf16(a, b, c[ks & 3], 0, 0, 0);
        }
        f32x4 acc = (c[0] + c[1]) + (c[2] + c[3]);

        // prefetch next-step gumbel
        float gn0 = gq[0][scn * 16], gn1 = gq[1][scn * 16];
        float gn2 = gq[2][scn * 16], gn3 = gq[3][scn * 16];

        // PV B-frags for this step
        const ushort_t* vp = wtgtT4 + (size_t)scc * 4096 + lane * 8;
        short8v bvf[8];
        #pragma unroll
        for (int df = 0; df < 8; ++df) bvf[df] = *(const short8v*)(vp + df * 512);

        // stats + top2 + P write
        const int colv = scc * 16 + lrow;
        float g4[4] = {gc0, gc1, gc2, gc3};
        #pragma unroll
        for (int q = 0; q < 4; ++q) {
            float l = acc[q] + b2v;
            m_[q] = fmaxf(m_[q], l);
            float e1 = __expf(l);
            sE_[q] += e1; sEl_[q] = fmaf(e1, l, sEl_[q]);
            float a = l + g4[q];
            float p = __expf(2.0f * a);
            s2_[q] += p;
            if (a > a1_[q]) { a2_[q] = a1_[q]; i2_[q] = i1_[q]; a1_[q] = a; i1_[q] = colv; }
            else if (a > a2_[q]) { a2_[q] = a; i2_[q] = colv; }
            pw[(kgrp * 4 + q) * 20 + lrow] = p;
        }

        // PV: transpose-read own P (same-wave), K=16 zero-padded MFMA
        {
            float4 p4 = *(const float4*)(pw + lrow * 20 + kgrp * 4);
            short8v pav;
            pav[0] = (short)f2bf(p4.x); pav[1] = (short)f2bf(p4.y);
            pav[2] = (short)f2bf(p4.z); pav[3] = (short)f2bf(p4.w);
            pav[4] = 0; pav[5] = 0; pav[6] = 0; pav[7] = 0;
            #pragma unroll
            for (int df = 0; df < 8; ++df)
                accpv[df] = __builtin_amdgcn_mfma_f32_16x16x32_bf16(pav, bvf[df], accpv[df], 0, 0, 0);
        }

        gc0 = gn0; gc1 = gn1; gc2 = gn2; gc3 = gn3;
        scc = scn;
    }

    // ---- in-wave reduction over the 16 lrow lanes ----
    #pragma unroll
    for (int q = 0; q < 4; ++q) {
        #pragma unroll
        for (int mk = 1; mk < 16; mk <<= 1) {
            m_[q] = fmaxf(m_[q], __shfl_xor(m_[q], mk));
            sE_[q] += __shfl_xor(sE_[q], mk);
            sEl_[q] += __shfl_xor(sEl_[q], mk);
            s2_[q] += __shfl_xor(s2_[q], mk);
            float ob1 = __shfl_xor(a1_[q], mk); int oj1 = __shfl_xor(i1_[q], mk);
            float ob2 = __shfl_xor(a2_[q], mk); int oj2 = __shfl_xor(i2_[q], mk);
            if (ob1 > a1_[q] || (ob1 == a1_[q] && oj1 < i1_[q])) {
                if (a1_[q] > ob2 || (a1_[q] == ob2 && i1_[q] < oj2)) { a2_[q] = a1_[q]; i2_[q] = i1_[q]; }
                else { a2_[q] = ob2; i2_[q] = oj2; }
                a1_[q] = ob1; i1_[q] = oj1;
            } else {
                if (ob1 > a2_[q]) { a2_[q] = ob1; i2_[q] = oj1; }
            }
        }
    }

    __syncthreads();   // all waves done with aP; scratch reuse safe

    // ---- publish partials ----
    if (lrow == 0) {
        #pragma unroll
        for (int q = 0; q < 4; ++q) {
            float* st = &statP[wid][kgrp * 4 + q][0];
            st[0] = m_[q]; st[1] = sE_[q]; st[2] = sEl_[q]; st[3] = s2_[q];
            st[4] = a1_[q]; st[5] = __int_as_float(i1_[q]);
            st[6] = a2_[q]; st[7] = __int_as_float(i2_[q]);
        }
    }
    if (wid >= 1) {
        float* scr = bigS + (wid - 1) * 2048;
        #pragma unroll
        for (int df = 0; df < 8; ++df)
            #pragma unroll
            for (int q = 0; q < 4; ++q)
                scr[(kgrp * 4 + q) * 128 + df * 16 + lrow] = accpv[df][q];
    }
    __syncthreads();

    // ---- wave 0: merge + scalar outputs + x_emb ----
    if (wid == 0) {
        float invs2_[4]; int msk_[4];
        float es = 0.f; int cs = 0;
        #pragma unroll
        for (int q = 0; q < 4; ++q) {
            int r = kgrp * 4 + q;
            float M = m_[q], SE = sE_[q], SEL = sEl_[q], S2 = s2_[q];
            float A1 = a1_[q], A2 = a2_[q]; int I1 = i1_[q], I2 = i2_[q];
            #pragma unroll
            for (int w = 1; w < 4; ++w) {
                const float* st = &statP[w][r][0];
                float ob1 = st[4]; int oj1 = __float_as_int(st[5]);
                float ob2 = st[6]; int oj2 = __float_as_int(st[7]);
                M = fmaxf(M, st[0]); SE += st[1]; SEL += st[2]; S2 += st[3];
                if (ob1 > A1 || (ob1 == A1 && oj1 < I1)) {
                    if (A1 > ob2 || (A1 == ob2 && I1 < oj2)) { A2 = A1; I2 = I1; }
                    else { A2 = ob2; I2 = oj2; }
                    A1 = ob1; I1 = oj1;
                } else {
                    if (ob1 > A2) { A2 = ob1; I2 = oj1; }
                }
            }
            invs2_[q] = 1.0f / S2;
            int grow = row0 + r;
            int w_in = inp_word[grow];
            int msk = keyword_table[w_in] != 0;
            msk_[q] = msk;
            float entq = msk ? (__logf(SE) - SEL / SE) : 0.0f;
            es += entq; cs += msk;
            if (lrow == 0) {
                out[MASK_OFF + grow] = msk ? 1.0f : 0.0f;
                out[LOGP_OFF + grow] = msk ? M : 0.0f;
                mskS[r] = msk;
                candS[r * 2 + 0] = I1;
                candS[r * 2 + 1] = I2;
            }
        }
        // loss partials (sum over the 4 kgrp groups)
        {
            float e0 = __shfl(es, 0), e16 = __shfl(es, 16), e32 = __shfl(es, 32), e48 = __shfl(es, 48);
            int c0 = __shfl(cs, 0), c16 = __shfl(cs, 16), c32 = __shfl(cs, 32), c48 = __shfl(cs, 48);
            if (lane == 0) {
                entP[blockIdx.x] = e0 + e16 + e32 + e48;
                cntP[blockIdx.x] = (float)(c0 + c16 + c32 + c48);
            }
        }
        // merge PV partials + store x_emb
        #pragma unroll
        for (int df = 0; df < 8; ++df) {
            #pragma unroll
            for (int q = 0; q < 4; ++q) {
                int r = kgrp * 4 + q;
                float v = accpv[df][q]
                        + bigS[0 * 2048 + r * 128 + df * 16 + lrow]
                        + bigS[1 * 2048 + r * 128 + df * 16 + lrow]
                        + bigS[2 * 2048 + r * 128 + df * 16 + lrow];
                int grow = row0 + r;
                int d = df * 16 + lrow;
                float val = v * invs2_[q];
                if (!msk_[q]) val = x[(size_t)grow * DD + d];
                out[EMB_OFF + (size_t)grow * DD + d] = val;
            }
        }
    }
    __syncthreads();

    // ---- repair + word/char: wave wid handles rows wid, wid+4, wid+8, wid+12 ----
    for (int rr = wid; rr < 16; rr += 4) {
        int grow = row0 + rr;
        int i1 = candS[rr * 2 + 0], i2 = candS[rr * 2 + 1];
        int mskr = mskS[rr];
        const float* hrow = hdn + (size_t)grow * HH;
        float4 h0 = *(const float4*)(hrow + lane * 8);
        float4 h1 = *(const float4*)(hrow + lane * 8 + 4);
        float v1, v2;
        {
            const float* wrow = W2Tf + (size_t)i1 * HH;
            float4 w0 = *(const float4*)(wrow + lane * 8);
            float4 w1 = *(const float4*)(wrow + lane * 8 + 4);
            float sdot = h0.x*w0.x + h0.y*w0.y + h0.z*w0.z + h0.w*w0.w
                       + h1.x*w1.x + h1.y*w1.y + h1.z*w1.z + h1.w*w1.w;
            #pragma unroll
            for (int mk = 1; mk < 64; mk <<= 1) sdot += __shfl_xor(sdot, mk);
            v1 = sdot + b2[i1] + gumbel[(size_t)grow * T_NT + i1];
        }
        {
            const float* wrow = W2Tf + (size_t)i2 * HH;
            float4 w0 = *(const float4*)(wrow + lane * 8);
            float4 w1 = *(const float4*)(wrow + lane * 8 + 4);
            float sdot = h0.x*w0.x + h0.y*w0.y + h0.z*w0.z + h0.w*w0.w
                       + h1.x*w1.x + h1.y*w1.y + h1.z*w1.z + h1.w*w1.w;
            #pragma unroll
            for (int mk = 1; mk < 64; mk <<= 1) sdot += __shfl_xor(sdot, mk);
            v2 = sdot + b2[i2] + gumbel[(size_t)grow * T_NT + i2];
        }
        int ibest = (v2 > v1 || (v2 == v1 && i2 < i1)) ? i2 : i1;
        int word = mskr ? tgt_ids[ibest] : inp_word[grow];
        if (lane == 0) out[WORD_OFF + grow] = (float)word;
        if (lane < MC_)
            out[CHAR_OFF + (size_t)grow * MC_ + lane] = (float)lut[(size_t)word * MC_ + lane];
    }
}

// ---------------- K4: final loss reduction ----------------
__global__ __launch_bounds__(256) void k4_loss(
    const float* __restrict__ entP, const float* __restrict__ cntP, float* __restrict__ out)
{
    __shared__ float sE[256], sC[256];
    int t = threadIdx.x;
    float e = 0.f, c = 0.f;
    for (int i = t; i < NBLK; i += 256) { e += entP[i]; c += cntP[i]; }
    sE[t] = e; sC[t] = c;
    __syncthreads();
    for (int s = 128; s > 0; s >>= 1) {
        if (t < s) { sE[t] += sE[t + s]; sC[t] += sC[t + s]; }
        __syncthreads();
    }
    if (t == 0) {
        float ns = fmaxf(sC[0], 1.0f);
        out[LOSS_OFF] = 0.03f * sE[0] / ns;
    }
}

// ---------------- launch ----------------
extern "C" void kernel_launch(void* const* d_in, const int* in_sizes, int n_in,
                              void* d_out, int out_size, void* d_ws, size_t ws_size,
                              hipStream_t stream) {
    const int* inp_word = (const int*)d_in[0];
    const int* keyword_table = (const int*)d_in[3];
    const int* tgt_ids = (const int*)d_in[4];
    const int* lut = (const int*)d_in[5];
    const float* gumbel = (const float*)d_in[6];
    const float* W = (const float*)d_in[7];
    const float* W1 = (const float*)d_in[8];
    const float* b1 = (const float*)d_in[9];
    const float* W2 = (const float*)d_in[10];
    const float* b2 = (const float*)d_in[11];
    float* out = (float*)d_out;

    float* wsf = (float*)d_ws;
    float* x = wsf + X_OFF;
    float* hdn = wsf + HDN_OFF;
    ushort_t* hdnB = (ushort_t*)(wsf + HDNB_OFF);
    float* wtgt = wsf + WT_OFF;
    ushort_t* wtgtT4 = (ushort_t*)(wsf + WTT4_OFF);
    float* W2Tf = wsf + W2T_OFF;
    ushort_t* W2p = (ushort_t*)(wsf + W2P_OFF);
    float* entP = wsf + WT_OFF;          // wtgt region dead after k1b
    float* cntP = wsf + WT_OFF + 1024;

    k1_gather<<<(R_TOT + T_NT) / 2, 256, 0, stream>>>(inp_word, tgt_ids, W, x, wtgt);
    k1b_wtgtT4<<<64, 256, 0, stream>>>(wtgt, wtgtT4);
    k0_w2t<<<dim3(T_NT / 32, HH / 32), 256, 0, stream>>>(W2, W2Tf, W2p);
    k2_hdn<<<dim3(R_TOT / 64, HH / 64), 256, 0, stream>>>(x, W1, b1, hdn, hdnB);
    k3_fused<<<NBLK, 256, 0, stream>>>(hdnB, hdn, W2p, W2Tf, b2, gumbel,
                                       inp_word, keyword_table, tgt_ids, lut,
                                       x, wtgtT4, out, entP, cntP);
    k4_loss<<<1, 256, 0, stream>>>(entP, cntP, out);
}

// Round 10
// 299.186 us; speedup vs baseline: 2.4990x; 2.3533x over previous
//
#include <hip/hip_runtime.h>
#include <cstdint>

#define R_TOT 16384
#define T_NT  2048
#define DD    128
#define HH    512
#define MC_   20
#define BR    32             // rows per block in k3
#define STEPS 64             // 2048 / 32 cols
#define NBLK  (R_TOT / BR)   // 512

// Output layout (floats)
#define MASK_OFF 0
#define LOGP_OFF 16384
#define WORD_OFF 32768
#define CHAR_OFF 49152
#define EMB_OFF  376832          // 49152 + 16384*20
#define LOSS_OFF 2473984         // 376832 + 16384*128

// ws layout (float slots)
#define X_OFF     0              // x f32 [16384][128]
#define HDN_OFF   2097152        // hdn f32 [16384][512]
#define HDNB_OFF  10485760       // hdn bf16 ushort[16384*512]
#define WT_OFF    14680064       // wtgt f32 [2048][128]
#define WTT4_OFF  14942208       // wtgtT4 ushort[128][8][64][8]  (524288)
#define W2T_OFF   15204352       // W2Tf f32 [2048][512]
#define W2P_OFF   16252928       // W2p ushort[64][16][32][4][8]  (1048576)
#define ENT_OFF   16777216       // 512
#define CNT_OFF   16777728       // 512

typedef __attribute__((ext_vector_type(8))) short short8v;
typedef __attribute__((ext_vector_type(4))) float f32x4;
typedef unsigned short ushort_t;

__device__ __forceinline__ ushort_t f2bf(float f) {
    union { float f; unsigned int u; } v; v.f = f;
    unsigned int r = v.u + 0x7FFFu + ((v.u >> 16) & 1u);
    return (ushort_t)(r >> 16);
}

__device__ __forceinline__ void stage16(const ushort_t* gsrc, ushort_t* ldst) {
    __builtin_amdgcn_global_load_lds(
        (const __attribute__((address_space(1))) unsigned int*)gsrc,
        (__attribute__((address_space(3))) unsigned int*)ldst, 16, 0, 0);
}

// ---------------- K1: gather embeddings ----------------
__global__ __launch_bounds__(256) void k1_gather(
    const int* __restrict__ inp_word, const int* __restrict__ tgt_ids,
    const float* __restrict__ W, float* __restrict__ x, float* __restrict__ wtgt)
{
    int row = blockIdx.x * 2 + (threadIdx.x >> 7);
    int d = threadIdx.x & 127;
    if (row < R_TOT) {
        int wsrc = inp_word[row];
        x[(size_t)row * DD + d] = W[(size_t)wsrc * DD + d];
    } else {
        int rr = row - R_TOT;
        if (rr < T_NT) {
            int wsrc = tgt_ids[rr];
            wtgt[(size_t)rr * DD + d] = W[(size_t)wsrc * DD + d];
        }
    }
}

// ---------------- K1b: wtgt -> wtgtT4 PV B-fragment pack ----------------
// wtgtT4[((js*2+cs)*8+df)*512 + lane*8 + j] =
//   j<4 ? bf16(wtgt[js*32+cs*16+(lane>>4)*4+j][df*16+(lane&15)]) : 0
__global__ __launch_bounds__(256) void k1b_wtgtT4(
    const float* __restrict__ wtgt, ushort_t* __restrict__ wtgtT4)
{
    const int js = blockIdx.x, t = threadIdx.x;
    #pragma unroll
    for (int i = 0; i < 4; ++i) {
        int s = i * 256 + t;
        int cs = s >> 9, rem = s & 511;
        int df = rem >> 6, lane = rem & 63;
        int lrow = lane & 15, kg = lane >> 4;
        ushort_t* dst = wtgtT4 + (size_t)(((js * 2 + cs) * 8 + df) * 512 + lane * 8);
        #pragma unroll
        for (int j = 0; j < 8; ++j) {
            dst[j] = (j < 4)
                ? f2bf(wtgt[(size_t)(js * 32 + cs * 16 + kg * 4 + j) * DD + df * 16 + lrow])
                : (ushort_t)0;
        }
    }
}

// ---------------- K0: W2 [512][2048] -> W2Tf f32 + W2p fragment pack ----------------
// W2p chunk (js,ks): 1024 ushorts; offset (c*4+kgrp)*8+i = bf16(W2[ks*32+kgrp*8+i][js*32+c])
__global__ __launch_bounds__(256) void k0_w2t(
    const float* __restrict__ W2, float* __restrict__ W2Tf, ushort_t* __restrict__ W2p)
{
    __shared__ float tile[32][33];
    const int js = blockIdx.x, ks = blockIdx.y;
    const int cb = js * 32, kb = ks * 32;
    const int lx = threadIdx.x & 31, ly = threadIdx.x >> 5;
    #pragma unroll
    for (int i = 0; i < 32; i += 8)
        tile[ly + i][lx] = W2[(size_t)(kb + ly + i) * T_NT + cb + lx];
    __syncthreads();
    #pragma unroll
    for (int i = 0; i < 32; i += 8) {
        int c = cb + ly + i, k = kb + lx;
        W2Tf[(size_t)c * HH + k] = tile[lx][ly + i];
    }
    if (threadIdx.x < 128) {
        int c = threadIdx.x >> 2, kgrp = threadIdx.x & 3;
        ushort_t* dst = W2p + (size_t)((js * 16 + ks) * 1024 + (c * 4 + kgrp) * 8);
        #pragma unroll
        for (int i = 0; i < 8; ++i)
            dst[i] = f2bf(tile[kgrp * 8 + i][c]);
    }
}

// ---------------- K2: hdn = relu(x @ W1 + b1), fp32 + bf16 outputs ----------------
__global__ __launch_bounds__(256) void k2_hdn(
    const float* __restrict__ x, const float* __restrict__ W1,
    const float* __restrict__ b1, float* __restrict__ hdn, ushort_t* __restrict__ hdnB)
{
    __shared__ float As[16][64];
    __shared__ float Bs[16][64];
    const int t = threadIdx.x;
    const int bm = blockIdx.x * 64;
    const int bn = blockIdx.y * 64;
    const int tx = t & 15, ty = t >> 4;
    float acc[4][4] = {};
    for (int k0 = 0; k0 < DD; k0 += 16) {
        {
            int m = t >> 2, kq = t & 3;
            float4 v = *(const float4*)(x + (size_t)(bm + m) * DD + k0 + kq * 4);
            As[kq * 4 + 0][m] = v.x; As[kq * 4 + 1][m] = v.y;
            As[kq * 4 + 2][m] = v.z; As[kq * 4 + 3][m] = v.w;
        }
        {
            int k = t >> 4, nq = t & 15;
            *(float4*)(&Bs[k][nq * 4]) =
                *(const float4*)(W1 + (size_t)(k0 + k) * HH + bn + nq * 4);
        }
        __syncthreads();
        #pragma unroll
        for (int k = 0; k < 16; ++k) {
            float a[4], b[4];
            #pragma unroll
            for (int i = 0; i < 4; i++) a[i] = As[k][ty * 4 + i];
            #pragma unroll
            for (int j = 0; j < 4; j++) b[j] = Bs[k][tx * 4 + j];
            #pragma unroll
            for (int i = 0; i < 4; i++)
                #pragma unroll
                for (int j = 0; j < 4; j++)
                    acc[i][j] = fmaf(a[i], b[j], acc[i][j]);
        }
        __syncthreads();
    }
    #pragma unroll
    for (int i = 0; i < 4; i++) {
        int m = bm + ty * 4 + i;
        int n = bn + tx * 4;
        float4 v;
        v.x = fmaxf(acc[i][0] + b1[n + 0], 0.f);
        v.y = fmaxf(acc[i][1] + b1[n + 1], 0.f);
        v.z = fmaxf(acc[i][2] + b1[n + 2], 0.f);
        v.w = fmaxf(acc[i][3] + b1[n + 3], 0.f);
        *(float4*)(hdn + (size_t)m * HH + n) = v;
        ushort4 hb;
        hb.x = f2bf(v.x); hb.y = f2bf(v.y); hb.z = f2bf(v.z); hb.w = f2bf(v.w);
        *(ushort4*)(hdnB + (size_t)m * HH + n) = hb;
    }
}

// ---------------- K3: single-buffer staged fused kernel, 2 barriers/step ----------------
// 512 blocks x 32 rows, 4 waves = 2 Mgrp x 2 Cgrp. LDS ~39 KB -> 3 blocks/CU (reg-bound).
// Step: [A: consume wS] bar [B: stage s+1 + stats/P/PV (no wS)] bar.
__global__ __launch_bounds__(256) void k3_fused(
    const ushort_t* __restrict__ hdnB, const float* __restrict__ hdn,
    const ushort_t* __restrict__ W2p, const float* __restrict__ W2Tf,
    const float* __restrict__ b2, const float* __restrict__ gumbel,
    const int* __restrict__ inp_word, const int* __restrict__ keyword_table,
    const int* __restrict__ tgt_ids, const int* __restrict__ lut,
    const float* __restrict__ x, const ushort_t* __restrict__ wtgtT4,
    float* __restrict__ out, float* __restrict__ entP, float* __restrict__ cntP)
{
    __shared__ ushort_t wS[16384];          // 32 KB single-buffered W2p tile; scratch later
    __shared__ float pS[4][16 * 20];        // wave-private P transpose (pad 20)
    __shared__ float statC1[2 * 16 * 8];
    __shared__ int   candS[BR * 2];
    __shared__ float invs2S[BR], entS[BR];
    __shared__ int   mskS[BR];

    const int t = threadIdx.x;
    const int wid = t >> 6, lane = t & 63;
    const int Mgrp = wid >> 1, Cgrp = wid & 1;
    const int lrow = lane & 15, kgrp = lane >> 4;
    const int row0 = blockIdx.x * BR;
    const int rowA = row0 + Mgrp * 16 + lrow;

    // ---- A fragments: full K in registers ----
    short8v av[16];
    #pragma unroll
    for (int ks = 0; ks < 16; ++ks)
        av[ks] = *(const short8v*)(hdnB + (size_t)rowA * HH + ks * 32 + kgrp * 8);

    // ---- B read base (loop-invariant + ks*1024 ushort imm) ----
    const ushort_t* wb = wS + ((Cgrp * 16 + lrow) * 4 + kgrp) * 8;

    // ---- running pointers ----
    const float* gp0 = gumbel + (size_t)(row0 + Mgrp * 16 + kgrp * 4 + 0) * T_NT + Cgrp * 16 + lrow;
    const float* gp1 = gp0 + T_NT;
    const float* gp2 = gp1 + T_NT;
    const float* gp3 = gp2 + T_NT;
    const float* b2p = b2 + Cgrp * 16 + lrow;
    const ushort_t* vtp = wtgtT4 + (size_t)Cgrp * 4096 + lane * 8;

    float* pw = &pS[wid][0];

    // ---- stats ----
    float m_[4], sE_[4], sEl_[4], s2_[4], a1_[4], a2_[4];
    int i1_[4], i2_[4];
    #pragma unroll
    for (int q = 0; q < 4; ++q) {
        m_[q] = -1e30f; sE_[q] = 0.f; sEl_[q] = 0.f; s2_[q] = 0.f;
        a1_[q] = -1e30f; a2_[q] = -1e30f; i1_[q] = 0; i2_[q] = 0;
    }
    f32x4 accpv[8];
    #pragma unroll
    for (int df = 0; df < 8; ++df) accpv[df] = (f32x4){0.f, 0.f, 0.f, 0.f};

    // ---- prologue: stage tile 0; load step-0 scalars ----
    {
        const ushort_t* src = W2p + t * 8;
        ushort_t* dst = wS + t * 8;
        #pragma unroll
        for (int i = 0; i < 8; ++i) stage16(src + i * 2048, dst + i * 2048);
    }
    float g0 = *gp0, g1 = *gp1, g2 = *gp2, g3 = *gp3;
    float b2v = *b2p;
    __syncthreads();   // tile 0 resident

    int colv = Cgrp * 16 + lrow;

    for (int s = 0; s < STEPS; ++s) {
        // ---- phase A: S tile from wS (16 MFMA, 4 chains, imm ds_reads) ----
        f32x4 ac0 = (f32x4){0.f,0.f,0.f,0.f}, ac1 = ac0, ac2 = ac0, ac3 = ac0;
        #pragma unroll
        for (int ks = 0; ks < 16; ks += 4) {
            ac0 = __builtin_amdgcn_mfma_f32_16x16x32_bf16(av[ks+0], *(const short8v*)(wb + (ks+0)*1024), ac0, 0, 0, 0);
            ac1 = __builtin_amdgcn_mfma_f32_16x16x32_bf16(av[ks+1], *(const short8v*)(wb + (ks+1)*1024), ac1, 0, 0, 0);
            ac2 = __builtin_amdgcn_mfma_f32_16x16x32_bf16(av[ks+2], *(const short8v*)(wb + (ks+2)*1024), ac2, 0, 0, 0);
            ac3 = __builtin_amdgcn_mfma_f32_16x16x32_bf16(av[ks+3], *(const short8v*)(wb + (ks+3)*1024), ac3, 0, 0, 0);
        }
        f32x4 acc = (ac0 + ac1) + (ac2 + ac3);

        __syncthreads();   // #1: all waves done reading wS

        // ---- phase B: stage next tile + non-wS work ----
        if (s + 1 < STEPS) {
            const ushort_t* src = W2p + (size_t)(s + 1) * 16384 + t * 8;
            ushort_t* dst = wS + t * 8;
            #pragma unroll
            for (int i = 0; i < 8; ++i) stage16(src + i * 2048, dst + i * 2048);
        }
        // next-step scalar prefetch
        gp0 += 32; gp1 += 32; gp2 += 32; gp3 += 32; b2p += 32;
        float gn0 = *gp0, gn1 = *gp1, gn2 = *gp2, gn3 = *gp3;
        float b2n = *b2p;
        // PV B-frags for current step (L2)
        short8v bvf[8];
        #pragma unroll
        for (int df = 0; df < 8; ++df)
            bvf[df] = *(const short8v*)(vtp + df * 512);
        vtp += 8192;

        // stats + top2 + P write (wave-private)
        float g4[4] = {g0, g1, g2, g3};
        #pragma unroll
        for (int q = 0; q < 4; ++q) {
            float l = acc[q] + b2v;
            m_[q] = fmaxf(m_[q], l);
            float e1 = __expf(l);
            sE_[q] += e1; sEl_[q] = fmaf(e1, l, sEl_[q]);
            float a = l + g4[q];
            float p = __expf(2.0f * a);
            s2_[q] += p;
            if (a > a1_[q]) { a2_[q] = a1_[q]; i2_[q] = i1_[q]; a1_[q] = a; i1_[q] = colv; }
            else if (a > a2_[q]) { a2_[q] = a; i2_[q] = colv; }
            pw[(kgrp * 4 + q) * 20 + lrow] = p;
        }

        // PV: transpose-read own P (same-wave), K=16 zero-padded
        {
            float4 p4 = *(const float4*)(pw + lrow * 20 + kgrp * 4);
            short8v pav;
            pav[0] = (short)f2bf(p4.x); pav[1] = (short)f2bf(p4.y);
            pav[2] = (short)f2bf(p4.z); pav[3] = (short)f2bf(p4.w);
            pav[4] = 0; pav[5] = 0; pav[6] = 0; pav[7] = 0;
            #pragma unroll
            for (int df = 0; df < 8; ++df)
                accpv[df] = __builtin_amdgcn_mfma_f32_16x16x32_bf16(pav, bvf[df], accpv[df], 0, 0, 0);
        }

        __syncthreads();   // #2: staging drained (hidden under stats/PV), tile s+1 ready
        g0 = gn0; g1 = gn1; g2 = gn2; g3 = gn3; b2v = b2n;
        colv += 32;
    }

    // ---- in-wave reduction over the 16 lrow lanes ----
    #pragma unroll
    for (int q = 0; q < 4; ++q) {
        #pragma unroll
        for (int mk = 1; mk < 16; mk <<= 1) {
            m_[q] = fmaxf(m_[q], __shfl_xor(m_[q], mk));
            sE_[q] += __shfl_xor(sE_[q], mk);
            sEl_[q] += __shfl_xor(sEl_[q], mk);
            s2_[q] += __shfl_xor(s2_[q], mk);
            float ob1 = __shfl_xor(a1_[q], mk); int oj1 = __shfl_xor(i1_[q], mk);
            float ob2 = __shfl_xor(a2_[q], mk); int oj2 = __shfl_xor(i2_[q], mk);
            if (ob1 > a1_[q] || (ob1 == a1_[q] && oj1 < i1_[q])) {
                if (a1_[q] > ob2 || (a1_[q] == ob2 && i1_[q] < oj2)) { a2_[q] = a1_[q]; i2_[q] = i1_[q]; }
                else { a2_[q] = ob2; i2_[q] = oj2; }
                a1_[q] = ob1; i1_[q] = oj1;
            } else {
                if (ob1 > a2_[q]) { a2_[q] = ob1; i2_[q] = oj1; }
            }
        }
    }

    // ---- phase 1: Cgrp1 publishes stats + PV partials ----
    if (Cgrp == 1 && lrow == 0) {
        #pragma unroll
        for (int q = 0; q < 4; ++q) {
            float* st = &statC1[(Mgrp * 16 + kgrp * 4 + q) * 8];
            st[0] = m_[q]; st[1] = sE_[q]; st[2] = sEl_[q]; st[3] = s2_[q];
            st[4] = a1_[q]; st[5] = __int_as_float(i1_[q]);
            st[6] = a2_[q]; st[7] = __int_as_float(i2_[q]);
        }
    }
    float* scr = (float*)wS;   // 16 KB scratch: [Mgrp][16 rows][128 d]
    if (Cgrp == 1) {
        #pragma unroll
        for (int df = 0; df < 8; ++df)
            #pragma unroll
            for (int q = 0; q < 4; ++q)
                scr[Mgrp * 2048 + (kgrp * 4 + q) * 128 + df * 16 + lrow] = accpv[df][q];
    }
    __syncthreads();

    // ---- phase 2: Cgrp0 merges + writes scalar outputs ----
    if (Cgrp == 0) {
        float invs2_[4]; int mskq_[4];
        #pragma unroll
        for (int q = 0; q < 4; ++q) {
            int r = kgrp * 4 + q;
            const float* st = &statC1[(Mgrp * 16 + r) * 8];
            float bm = st[0], bsE = st[1], bsEl = st[2], bs2 = st[3];
            float ob1 = st[4]; int oj1 = __float_as_int(st[5]);
            float ob2 = st[6]; int oj2 = __float_as_int(st[7]);
            float m = fmaxf(m_[q], bm);
            float sE = sE_[q] + bsE, sEl = sEl_[q] + bsEl, s2 = s2_[q] + bs2;
            float a1 = a1_[q], a2 = a2_[q]; int i1 = i1_[q], i2 = i2_[q];
            if (ob1 > a1 || (ob1 == a1 && oj1 < i1)) {
                if (a1 > ob2 || (a1 == ob2 && i1 < oj2)) { a2 = a1; i2 = i1; }
                else { a2 = ob2; i2 = oj2; }
                a1 = ob1; i1 = oj1;
            } else {
                if (ob1 > a2) { a2 = ob1; i2 = oj1; }
            }
            if (lrow == 0) {
                int rl = Mgrp * 16 + r;
                int grow = row0 + rl;
                int w_in = inp_word[grow];
                int msk = keyword_table[w_in] != 0;
                out[MASK_OFF + grow] = msk ? 1.0f : 0.0f;
                out[LOGP_OFF + grow] = msk ? m : 0.0f;
                invs2S[rl] = 1.0f / s2;
                mskS[rl] = msk;
                entS[rl] = msk ? (__logf(sE) - sEl / sE) : 0.0f;
                candS[rl * 2 + 0] = i1;
                candS[rl * 2 + 1] = i2;
            }
        }
        #pragma unroll
        for (int df = 0; df < 8; ++df)
            #pragma unroll
            for (int q = 0; q < 4; ++q)
                accpv[df][q] += scr[Mgrp * 2048 + (kgrp * 4 + q) * 128 + df * 16 + lrow];
        (void)invs2_; (void)mskq_;
    }
    __syncthreads();

    // ---- x_emb store (Cgrp0 waves, full d) ----
    if (Cgrp == 0) {
        #pragma unroll
        for (int df = 0; df < 8; ++df) {
            #pragma unroll
            for (int q = 0; q < 4; ++q) {
                int rl = Mgrp * 16 + kgrp * 4 + q;
                int grow = row0 + rl;
                int d = df * 16 + lrow;
                float val = accpv[df][q] * invs2S[rl];
                if (!mskS[rl]) val = x[(size_t)grow * DD + d];
                out[EMB_OFF + (size_t)grow * DD + d] = val;
            }
        }
    }

    // ---- repair + word/char outputs: wave wid handles rows wid, wid+4, ... ----
    for (int rr = wid; rr < BR; rr += 4) {
        int grow = row0 + rr;
        int i1 = candS[rr * 2 + 0], i2 = candS[rr * 2 + 1];
        const float* hrow = hdn + (size_t)grow * HH;
        float4 h0 = *(const float4*)(hrow + lane * 8);
        float4 h1 = *(const float4*)(hrow + lane * 8 + 4);
        float v1, v2;
        {
            const float* wrow = W2Tf + (size_t)i1 * HH;
            float4 w0 = *(const float4*)(wrow + lane * 8);
            float4 w1 = *(const float4*)(wrow + lane * 8 + 4);
            float sdot = h0.x*w0.x + h0.y*w0.y + h0.z*w0.z + h0.w*w0.w
                       + h1.x*w1.x + h1.y*w1.y + h1.z*w1.z + h1.w*w1.w;
            #pragma unroll
            for (int mk = 1; mk < 64; mk <<= 1) sdot += __shfl_xor(sdot, mk);
            v1 = sdot + b2[i1] + gumbel[(size_t)grow * T_NT + i1];
        }
        {
            const float* wrow = W2Tf + (size_t)i2 * HH;
            float4 w0 = *(const float4*)(wrow + lane * 8);
            float4 w1 = *(const float4*)(wrow + lane * 8 + 4);
            float sdot = h0.x*w0.x + h0.y*w0.y + h0.z*w0.z + h0.w*w0.w
                       + h1.x*w1.x + h1.y*w1.y + h1.z*w1.z + h1.w*w1.w;
            #pragma unroll
            for (int mk = 1; mk < 64; mk <<= 1) sdot += __shfl_xor(sdot, mk);
            v2 = sdot + b2[i2] + gumbel[(size_t)grow * T_NT + i2];
        }
        int ibest = (v2 > v1 || (v2 == v1 && i2 < i1)) ? i2 : i1;
        int w_in = inp_word[grow];
        int msk = mskS[rr];
        int word = msk ? tgt_ids[ibest] : w_in;
        if (lane == 0) out[WORD_OFF + grow] = (float)word;
        if (lane < MC_)
            out[CHAR_OFF + (size_t)grow * MC_ + lane] = (float)lut[(size_t)word * MC_ + lane];
    }

    if (t == 0) {
        float es = 0.f; int cs = 0;
        #pragma unroll
        for (int r = 0; r < BR; r++) { es += entS[r]; cs += mskS[r]; }
        entP[blockIdx.x] = es;
        cntP[blockIdx.x] = (float)cs;
    }
}

// ---------------- K4: final loss reduction ----------------
__global__ __launch_bounds__(256) void k4_loss(
    const float* __restrict__ entP, const float* __restrict__ cntP, float* __restrict__ out)
{
    __shared__ float sE[256], sC[256];
    int t = threadIdx.x;
    float e = 0.f, c = 0.f;
    for (int i = t; i < NBLK; i += 256) { e += entP[i]; c += cntP[i]; }
    sE[t] = e; sC[t] = c;
    __syncthreads();
    for (int s = 128; s > 0; s >>= 1) {
        if (t < s) { sE[t] += sE[t + s]; sC[t] += sC[t + s]; }
        __syncthreads();
    }
    if (t == 0) {
        float ns = fmaxf(sC[0], 1.0f);
        out[LOSS_OFF] = 0.03f * sE[0] / ns;
    }
}

// ---------------- launch ----------------
extern "C" void kernel_launch(void* const* d_in, const int* in_sizes, int n_in,
                              void* d_out, int out_size, void* d_ws, size_t ws_size,
                              hipStream_t stream) {
    const int* inp_word = (const int*)d_in[0];
    const int* keyword_table = (const int*)d_in[3];
    const int* tgt_ids = (const int*)d_in[4];
    const int* lut = (const int*)d_in[5];
    const float* gumbel = (const float*)d_in[6];
    const float* W = (const float*)d_in[7];
    const float* W1 = (const float*)d_in[8];
    const float* b1 = (const float*)d_in[9];
    const float* W2 = (const float*)d_in[10];
    const float* b2 = (const float*)d_in[11];
    float* out = (float*)d_out;

    float* wsf = (float*)d_ws;
    float* x = wsf + X_OFF;
    float* hdn = wsf + HDN_OFF;
    ushort_t* hdnB = (ushort_t*)(wsf + HDNB_OFF);
    float* wtgt = wsf + WT_OFF;
    ushort_t* wtgtT4 = (ushort_t*)(wsf + WTT4_OFF);
    float* W2Tf = wsf + W2T_OFF;
    ushort_t* W2p = (ushort_t*)(wsf + W2P_OFF);
    float* entP = wsf + ENT_OFF;
    float* cntP = wsf + CNT_OFF;

    k1_gather<<<(R_TOT + T_NT) / 2, 256, 0, stream>>>(inp_word, tgt_ids, W, x, wtgt);
    k1b_wtgtT4<<<64, 256, 0, stream>>>(wtgt, wtgtT4);
    k0_w2t<<<dim3(T_NT / 32, HH / 32), 256, 0, stream>>>(W2, W2Tf, W2p);
    k2_hdn<<<dim3(R_TOT / 64, HH / 64), 256, 0, stream>>>(x, W1, b1, hdn, hdnB);
    k3_fused<<<NBLK, 256, 0, stream>>>(hdnB, hdn, W2p, W2Tf, b2, gumbel,
                                       inp_word, keyword_table, tgt_ids, lut,
                                       x, wtgtT4, out, entP, cntP);
    k4_loss<<<1, 256, 0, stream>>>(entP, cntP, out);
}

// Round 11
// 206.159 us; speedup vs baseline: 3.6266x; 1.4512x over previous
//
#include <hip/hip_runtime.h>
#include <cstdint>

#define R_TOT 16384
#define T_NT  2048
#define DD    128
#define HH    512
#define MC_   20
#define BR    32             // rows per block in k3
#define STEPS 64             // 2048 / 32 cols
#define NBLK  (R_TOT / BR)   // 512

// Output layout (floats)
#define MASK_OFF 0
#define LOGP_OFF 16384
#define WORD_OFF 32768
#define CHAR_OFF 49152
#define EMB_OFF  376832          // 49152 + 16384*20
#define LOSS_OFF 2473984         // 376832 + 16384*128

// ws layout (float slots)
#define X_OFF     0              // x f32 [16384][128]
#define HDN_OFF   2097152        // hdn f32 [16384][512]
#define HDNB_OFF  10485760       // hdn bf16 ushort[16384*512]
#define WT_OFF    14680064       // wtgt f32 [2048][128]
#define WTT4_OFF  14942208       // wtgtT4 ushort[128][8][64][8]  (524288)
#define W2T_OFF   15204352       // W2Tf f32 [2048][512]
#define W2P_OFF   16252928       // W2p ushort[64][16][32][4][8]  (1048576)
#define ENT_OFF   16777216       // 512
#define CNT_OFF   16777728       // 512

typedef __attribute__((ext_vector_type(8))) short short8v;
typedef __attribute__((ext_vector_type(4))) float f32x4;
typedef unsigned short ushort_t;

__device__ __forceinline__ ushort_t f2bf(float f) {
    union { float f; unsigned int u; } v; v.f = f;
    unsigned int r = v.u + 0x7FFFu + ((v.u >> 16) & 1u);
    return (ushort_t)(r >> 16);
}

__device__ __forceinline__ void stage16(const ushort_t* gsrc, ushort_t* ldst) {
    __builtin_amdgcn_global_load_lds(
        (const __attribute__((address_space(1))) unsigned int*)gsrc,
        (__attribute__((address_space(3))) unsigned int*)ldst, 16, 0, 0);
}

// ---------------- K1: gather embeddings ----------------
__global__ __launch_bounds__(256) void k1_gather(
    const int* __restrict__ inp_word, const int* __restrict__ tgt_ids,
    const float* __restrict__ W, float* __restrict__ x, float* __restrict__ wtgt)
{
    int row = blockIdx.x * 2 + (threadIdx.x >> 7);
    int d = threadIdx.x & 127;
    if (row < R_TOT) {
        int wsrc = inp_word[row];
        x[(size_t)row * DD + d] = W[(size_t)wsrc * DD + d];
    } else {
        int rr = row - R_TOT;
        if (rr < T_NT) {
            int wsrc = tgt_ids[rr];
            wtgt[(size_t)rr * DD + d] = W[(size_t)wsrc * DD + d];
        }
    }
}

// ---------------- K1b: wtgt -> wtgtT4 PV B-fragment pack ----------------
// wtgtT4[((js*2+cs)*8+df)*512 + lane*8 + j] =
//   j<4 ? bf16(wtgt[js*32+cs*16+(lane>>4)*4+j][df*16+(lane&15)]) : 0
__global__ __launch_bounds__(256) void k1b_wtgtT4(
    const float* __restrict__ wtgt, ushort_t* __restrict__ wtgtT4)
{
    const int js = blockIdx.x, t = threadIdx.x;
    #pragma unroll
    for (int i = 0; i < 4; ++i) {
        int s = i * 256 + t;
        int cs = s >> 9, rem = s & 511;
        int df = rem >> 6, lane = rem & 63;
        int lrow = lane & 15, kg = lane >> 4;
        ushort_t* dst = wtgtT4 + (size_t)(((js * 2 + cs) * 8 + df) * 512 + lane * 8);
        #pragma unroll
        for (int j = 0; j < 8; ++j) {
            dst[j] = (j < 4)
                ? f2bf(wtgt[(size_t)(js * 32 + cs * 16 + kg * 4 + j) * DD + df * 16 + lrow])
                : (ushort_t)0;
        }
    }
}

// ---------------- K0: W2 [512][2048] -> W2Tf f32 + W2p fragment pack ----------------
// W2p chunk (js,ks): 1024 ushorts; offset (c*4+kgrp)*8+i = bf16(W2[ks*32+kgrp*8+i][js*32+c])
__global__ __launch_bounds__(256) void k0_w2t(
    const float* __restrict__ W2, float* __restrict__ W2Tf, ushort_t* __restrict__ W2p)
{
    __shared__ float tile[32][33];
    const int js = blockIdx.x, ks = blockIdx.y;
    const int cb = js * 32, kb = ks * 32;
    const int lx = threadIdx.x & 31, ly = threadIdx.x >> 5;
    #pragma unroll
    for (int i = 0; i < 32; i += 8)
        tile[ly + i][lx] = W2[(size_t)(kb + ly + i) * T_NT + cb + lx];
    __syncthreads();
    #pragma unroll
    for (int i = 0; i < 32; i += 8) {
        int c = cb + ly + i, k = kb + lx;
        W2Tf[(size_t)c * HH + k] = tile[lx][ly + i];
    }
    if (threadIdx.x < 128) {
        int c = threadIdx.x >> 2, kgrp = threadIdx.x & 3;
        ushort_t* dst = W2p + (size_t)((js * 16 + ks) * 1024 + (c * 4 + kgrp) * 8);
        #pragma unroll
        for (int i = 0; i < 8; ++i)
            dst[i] = f2bf(tile[kgrp * 8 + i][c]);
    }
}

// ---------------- K2: hdn = relu(x @ W1 + b1), fp32 + bf16 outputs ----------------
__global__ __launch_bounds__(256) void k2_hdn(
    const float* __restrict__ x, const float* __restrict__ W1,
    const float* __restrict__ b1, float* __restrict__ hdn, ushort_t* __restrict__ hdnB)
{
    __shared__ float As[16][64];
    __shared__ float Bs[16][64];
    const int t = threadIdx.x;
    const int bm = blockIdx.x * 64;
    const int bn = blockIdx.y * 64;
    const int tx = t & 15, ty = t >> 4;
    float acc[4][4] = {};
    for (int k0 = 0; k0 < DD; k0 += 16) {
        {
            int m = t >> 2, kq = t & 3;
            float4 v = *(const float4*)(x + (size_t)(bm + m) * DD + k0 + kq * 4);
            As[kq * 4 + 0][m] = v.x; As[kq * 4 + 1][m] = v.y;
            As[kq * 4 + 2][m] = v.z; As[kq * 4 + 3][m] = v.w;
        }
        {
            int k = t >> 4, nq = t & 15;
            *(float4*)(&Bs[k][nq * 4]) =
                *(const float4*)(W1 + (size_t)(k0 + k) * HH + bn + nq * 4);
        }
        __syncthreads();
        #pragma unroll
        for (int k = 0; k < 16; ++k) {
            float a[4], b[4];
            #pragma unroll
            for (int i = 0; i < 4; i++) a[i] = As[k][ty * 4 + i];
            #pragma unroll
            for (int j = 0; j < 4; j++) b[j] = Bs[k][tx * 4 + j];
            #pragma unroll
            for (int i = 0; i < 4; i++)
                #pragma unroll
                for (int j = 0; j < 4; j++)
                    acc[i][j] = fmaf(a[i], b[j], acc[i][j]);
        }
        __syncthreads();
    }
    #pragma unroll
    for (int i = 0; i < 4; i++) {
        int m = bm + ty * 4 + i;
        int n = bn + tx * 4;
        float4 v;
        v.x = fmaxf(acc[i][0] + b1[n + 0], 0.f);
        v.y = fmaxf(acc[i][1] + b1[n + 1], 0.f);
        v.z = fmaxf(acc[i][2] + b1[n + 2], 0.f);
        v.w = fmaxf(acc[i][3] + b1[n + 3], 0.f);
        *(float4*)(hdn + (size_t)m * HH + n) = v;
        ushort4 hb;
        hb.x = f2bf(v.x); hb.y = f2bf(v.y); hb.z = f2bf(v.z); hb.w = f2bf(v.w);
        *(ushort4*)(hdnB + (size_t)m * HH + n) = hb;
    }
}

// ---------------- K3: R6 structure + swapped S-MFMA (lane-local P) ----------------
// 512 blocks x 32 rows, 4 waves = 2 Mgrp x 2 Cgrp. Double-buffered W2p staging,
// one barrier/step. S computed as mfma(W2frag, hdnfrag) -> lane holds its own row's
// 4 cols; stats scalar per lane; PV A-operand built in-register (no P LDS).
__global__ __launch_bounds__(256) void k3_fused(
    const ushort_t* __restrict__ hdnB, const float* __restrict__ hdn,
    const ushort_t* __restrict__ W2p, const float* __restrict__ W2Tf,
    const float* __restrict__ b2, const float* __restrict__ gumbel,
    const int* __restrict__ inp_word, const int* __restrict__ keyword_table,
    const int* __restrict__ tgt_ids, const int* __restrict__ lut,
    const float* __restrict__ x, const ushort_t* __restrict__ wtgtT4,
    float* __restrict__ out, float* __restrict__ entP, float* __restrict__ cntP)
{
    __shared__ ushort_t wS[2 * 16384];      // 64 KB double-buffered W2p tiles; scratch later
    __shared__ float statC1[32 * 8];
    __shared__ int   candS[BR * 2];
    __shared__ float invs2S[BR], entS[BR];
    __shared__ int   mskS[BR];

    const int t = threadIdx.x;
    const int wid = t >> 6, lane = t & 63;
    const int Mgrp = wid >> 1, Cgrp = wid & 1;
    const int lrow = lane & 15, kgrp = lane >> 4;
    const int row0 = blockIdx.x * BR;
    const int rowA = row0 + Mgrp * 16 + lrow;

    // ---- hdn fragments (used as MFMA B operand after swap) ----
    short8v av[16];
    #pragma unroll
    for (int ks = 0; ks < 16; ++ks)
        av[ks] = *(const short8v*)(hdnB + (size_t)rowA * HH + ks * 32 + kgrp * 8);

    // ---- W2 A-frag read base (loop-invariant + ks*1024 ushort imm) ----
    const ushort_t* wb = wS + ((Cgrp * 16 + lrow) * 4 + kgrp) * 8;

    // ---- per-lane pointers: lane (r=lrow, kgrp) owns cols Cgrp*16+kgrp*4.. of row rowA
    const float* gp = gumbel + (size_t)rowA * T_NT + Cgrp * 16 + kgrp * 4;
    const float* b2p = b2 + Cgrp * 16 + kgrp * 4;
    const ushort_t* vtp = wtgtT4 + (size_t)Cgrp * 4096 + lane * 8;

    // ---- scalar stats (per lane = per row-slice) ----
    float m_ = -1e30f, sE_ = 0.f, sEl_ = 0.f, s2_ = 0.f;
    float a1_ = -1e30f, a2_ = -1e30f;
    int i1_ = 0, i2_ = 0;
    f32x4 accpv[8];
    #pragma unroll
    for (int df = 0; df < 8; ++df) accpv[df] = (f32x4){0.f, 0.f, 0.f, 0.f};

    // ---- prologue: stage tile 0 into buf 0; load step-0 scalars ----
    {
        const ushort_t* src = W2p + t * 8;
        ushort_t* dst = wS + t * 8;
        #pragma unroll
        for (int i = 0; i < 8; ++i) stage16(src + i * 2048, dst + i * 2048);
    }
    float4 g4 = *(const float4*)gp;
    float4 b2v4 = *(const float4*)b2p;
    __syncthreads();   // tile 0 resident

    int c0 = Cgrp * 16 + kgrp * 4;

    for (int s = 0; s < STEPS; ++s) {
        const int buf = s & 1;

        // 1) prefetch next W2p tile into buf^1 (consumed after this step's barrier)
        if (s + 1 < STEPS) {
            const ushort_t* src = W2p + (size_t)(s + 1) * 16384 + t * 8;
            ushort_t* dst = wS + (buf ^ 1) * 16384 + t * 8;
            #pragma unroll
            for (int i = 0; i < 8; ++i) stage16(src + i * 2048, dst + i * 2048);
        }
        // 2) prefetch next-step scalars + this step's PV B-frags
        const int adv = (s + 1 < STEPS) ? 32 : 0;
        float4 gn4 = *(const float4*)(gp + adv);
        float4 b2n4 = *(const float4*)(b2p + adv);
        gp += 32; b2p += 32;
        short8v bvf[8];
        #pragma unroll
        for (int df = 0; df < 8; ++df)
            bvf[df] = *(const short8v*)(vtp + df * 512);
        vtp += 8192;

        // 3) S tile, swapped operands: D = W2frag · hdnfrag -> lane holds S[r][c0..c0+3]
        const ushort_t* wbb = wb + buf * 16384;
        f32x4 ac0 = (f32x4){0.f,0.f,0.f,0.f}, ac1 = ac0, ac2 = ac0, ac3 = ac0;
        #pragma unroll
        for (int ks = 0; ks < 16; ks += 4) {
            ac0 = __builtin_amdgcn_mfma_f32_16x16x32_bf16(*(const short8v*)(wbb + (ks+0)*1024), av[ks+0], ac0, 0, 0, 0);
            ac1 = __builtin_amdgcn_mfma_f32_16x16x32_bf16(*(const short8v*)(wbb + (ks+1)*1024), av[ks+1], ac1, 0, 0, 0);
            ac2 = __builtin_amdgcn_mfma_f32_16x16x32_bf16(*(const short8v*)(wbb + (ks+2)*1024), av[ks+2], ac2, 0, 0, 0);
            ac3 = __builtin_amdgcn_mfma_f32_16x16x32_bf16(*(const short8v*)(wbb + (ks+3)*1024), av[ks+3], ac3, 0, 0, 0);
        }
        f32x4 acc = (ac0 + ac1) + (ac2 + ac3);

        // 4) stats + top2 + in-register P -> pav (lane-local, no LDS)
        short8v pav;
        pav[4] = 0; pav[5] = 0; pav[6] = 0; pav[7] = 0;
        #pragma unroll
        for (int q = 0; q < 4; ++q) {
            float l = acc[q] + b2v4[q];
            m_ = fmaxf(m_, l);
            float e1 = __expf(l);
            sE_ += e1; sEl_ = fmaf(e1, l, sEl_);
            float a = l + g4[q];
            float p = __expf(2.0f * a);
            s2_ += p;
            if (a > a1_) { a2_ = a1_; i2_ = i1_; a1_ = a; i1_ = c0 + q; }
            else if (a > a2_) { a2_ = a; i2_ = c0 + q; }
            pav[q] = (short)f2bf(p);
        }

        // 5) PV: A = pav (P rows, lane-local), B = wtgtT4 frags
        #pragma unroll
        for (int df = 0; df < 8; ++df)
            accpv[df] = __builtin_amdgcn_mfma_f32_16x16x32_bf16(pav, bvf[df], accpv[df], 0, 0, 0);

        g4 = gn4; b2v4 = b2n4; c0 += 32;
        __syncthreads();   // prefetch (issued at step top) landed; buf^1 ready
    }

    // ---- in-wave reduction across kgrp lanes (rows identical per lane&15) ----
    #pragma unroll
    for (int mk = 16; mk < 64; mk <<= 1) {
        m_ = fmaxf(m_, __shfl_xor(m_, mk));
        sE_ += __shfl_xor(sE_, mk);
        sEl_ += __shfl_xor(sEl_, mk);
        s2_ += __shfl_xor(s2_, mk);
        float ob1 = __shfl_xor(a1_, mk); int oj1 = __shfl_xor(i1_, mk);
        float ob2 = __shfl_xor(a2_, mk); int oj2 = __shfl_xor(i2_, mk);
        if (ob1 > a1_ || (ob1 == a1_ && oj1 < i1_)) {
            if (a1_ > ob2 || (a1_ == ob2 && i1_ < oj2)) { a2_ = a1_; i2_ = i1_; }
            else { a2_ = ob2; i2_ = oj2; }
            a1_ = ob1; i1_ = oj1;
        } else {
            if (ob1 > a2_) { a2_ = ob1; i2_ = oj1; }
        }
    }

    // ---- phase 1: Cgrp1 publishes stats + PV partials ----
    if (Cgrp == 1 && lane < 16) {
        float* st = &statC1[(Mgrp * 16 + lane) * 8];
        st[0] = m_; st[1] = sE_; st[2] = sEl_; st[3] = s2_;
        st[4] = a1_; st[5] = __int_as_float(i1_);
        st[6] = a2_; st[7] = __int_as_float(i2_);
    }
    float* scr = (float*)wS;   // scratch: [Mgrp][16 rows][128 d]
    if (Cgrp == 1) {
        #pragma unroll
        for (int df = 0; df < 8; ++df)
            #pragma unroll
            for (int q = 0; q < 4; ++q)
                scr[Mgrp * 2048 + (kgrp * 4 + q) * 128 + df * 16 + lrow] = accpv[df][q];
    }
    __syncthreads();

    // ---- phase 2: Cgrp0 merges ----
    if (Cgrp == 0) {
        if (lane < 16) {
            const float* st = &statC1[(Mgrp * 16 + lane) * 8];
            float bm = st[0], bsE = st[1], bsEl = st[2], bs2 = st[3];
            float ob1 = st[4]; int oj1 = __float_as_int(st[5]);
            float ob2 = st[6]; int oj2 = __float_as_int(st[7]);
            float m = fmaxf(m_, bm);
            float sE = sE_ + bsE, sEl = sEl_ + bsEl, s2 = s2_ + bs2;
            float a1 = a1_, a2 = a2_; int i1 = i1_, i2 = i2_;
            if (ob1 > a1 || (ob1 == a1 && oj1 < i1)) {
                if (a1 > ob2 || (a1 == ob2 && i1 < oj2)) { a2 = a1; i2 = i1; }
                else { a2 = ob2; i2 = oj2; }
                a1 = ob1; i1 = oj1;
            } else {
                if (ob1 > a2) { a2 = ob1; i2 = oj1; }
            }
            int rl = Mgrp * 16 + lane;
            int grow = row0 + rl;
            int w_in = inp_word[grow];
            int msk = keyword_table[w_in] != 0;
            out[MASK_OFF + grow] = msk ? 1.0f : 0.0f;
            out[LOGP_OFF + grow] = msk ? m : 0.0f;
            invs2S[rl] = 1.0f / s2;
            mskS[rl] = msk;
            entS[rl] = msk ? (__logf(sE) - sEl / sE) : 0.0f;
            candS[rl * 2 + 0] = i1;
            candS[rl * 2 + 1] = i2;
        }
        #pragma unroll
        for (int df = 0; df < 8; ++df)
            #pragma unroll
            for (int q = 0; q < 4; ++q)
                accpv[df][q] += scr[Mgrp * 2048 + (kgrp * 4 + q) * 128 + df * 16 + lrow];
    }
    __syncthreads();

    // ---- x_emb store (Cgrp0 waves, full d) ----
    if (Cgrp == 0) {
        #pragma unroll
        for (int df = 0; df < 8; ++df) {
            #pragma unroll
            for (int q = 0; q < 4; ++q) {
                int rl = Mgrp * 16 + kgrp * 4 + q;
                int grow = row0 + rl;
                int d = df * 16 + lrow;
                float val = accpv[df][q] * invs2S[rl];
                if (!mskS[rl]) val = x[(size_t)grow * DD + d];
                out[EMB_OFF + (size_t)grow * DD + d] = val;
            }
        }
    }

    // ---- repair + word/char outputs: wave wid handles rows wid, wid+4, ... ----
    for (int rr = wid; rr < BR; rr += 4) {
        int grow = row0 + rr;
        int i1 = candS[rr * 2 + 0], i2 = candS[rr * 2 + 1];
        const float* hrow = hdn + (size_t)grow * HH;
        float4 h0 = *(const float4*)(hrow + lane * 8);
        float4 h1 = *(const float4*)(hrow + lane * 8 + 4);
        float v1, v2;
        {
            const float* wrow = W2Tf + (size_t)i1 * HH;
            float4 w0 = *(const float4*)(wrow + lane * 8);
            float4 w1 = *(const float4*)(wrow + lane * 8 + 4);
            float sdot = h0.x*w0.x + h0.y*w0.y + h0.z*w0.z + h0.w*w0.w
                       + h1.x*w1.x + h1.y*w1.y + h1.z*w1.z + h1.w*w1.w;
            #pragma unroll
            for (int mk = 1; mk < 64; mk <<= 1) sdot += __shfl_xor(sdot, mk);
            v1 = sdot + b2[i1] + gumbel[(size_t)grow * T_NT + i1];
        }
        {
            const float* wrow = W2Tf + (size_t)i2 * HH;
            float4 w0 = *(const float4*)(wrow + lane * 8);
            float4 w1 = *(const float4*)(wrow + lane * 8 + 4);
            float sdot = h0.x*w0.x + h0.y*w0.y + h0.z*w0.z + h0.w*w0.w
                       + h1.x*w1.x + h1.y*w1.y + h1.z*w1.z + h1.w*w1.w;
            #pragma unroll
            for (int mk = 1; mk < 64; mk <<= 1) sdot += __shfl_xor(sdot, mk);
            v2 = sdot + b2[i2] + gumbel[(size_t)grow * T_NT + i2];
        }
        int ibest = (v2 > v1 || (v2 == v1 && i2 < i1)) ? i2 : i1;
        int w_in = inp_word[grow];
        int msk = mskS[rr];
        int word = msk ? tgt_ids[ibest] : w_in;
        if (lane == 0) out[WORD_OFF + grow] = (float)word;
        if (lane < MC_)
            out[CHAR_OFF + (size_t)grow * MC_ + lane] = (float)lut[(size_t)word * MC_ + lane];
    }

    if (t == 0) {
        float es = 0.f; int cs = 0;
        #pragma unroll
        for (int r = 0; r < BR; r++) { es += entS[r]; cs += mskS[r]; }
        entP[blockIdx.x] = es;
        cntP[blockIdx.x] = (float)cs;
    }
}

// ---------------- K4: final loss reduction ----------------
__global__ __launch_bounds__(256) void k4_loss(
    const float* __restrict__ entP, const float* __restrict__ cntP, float* __restrict__ out)
{
    __shared__ float sE[256], sC[256];
    int t = threadIdx.x;
    float e = 0.f, c = 0.f;
    for (int i = t; i < NBLK; i += 256) { e += entP[i]; c += cntP[i]; }
    sE[t] = e; sC[t] = c;
    __syncthreads();
    for (int s = 128; s > 0; s >>= 1) {
        if (t < s) { sE[t] += sE[t + s]; sC[t] += sC[t + s]; }
        __syncthreads();
    }
    if (t == 0) {
        float ns = fmaxf(sC[0], 1.0f);
        out[LOSS_OFF] = 0.03f * sE[0] / ns;
    }
}

// ---------------- launch ----------------
extern "C" void kernel_launch(void* const* d_in, const int* in_sizes, int n_in,
                              void* d_out, int out_size, void* d_ws, size_t ws_size,
                              hipStream_t stream) {
    const int* inp_word = (const int*)d_in[0];
    const int* keyword_table = (const int*)d_in[3];
    const int* tgt_ids = (const int*)d_in[4];
    const int* lut = (const int*)d_in[5];
    const float* gumbel = (const float*)d_in[6];
    const float* W = (const float*)d_in[7];
    const float* W1 = (const float*)d_in[8];
    const float* b1 = (const float*)d_in[9];
    const float* W2 = (const float*)d_in[10];
    const float* b2 = (const float*)d_in[11];
    float* out = (float*)d_out;

    float* wsf = (float*)d_ws;
    float* x = wsf + X_OFF;
    float* hdn = wsf + HDN_OFF;
    ushort_t* hdnB = (ushort_t*)(wsf + HDNB_OFF);
    float* wtgt = wsf + WT_OFF;
    ushort_t* wtgtT4 = (ushort_t*)(wsf + WTT4_OFF);
    float* W2Tf = wsf + W2T_OFF;
    ushort_t* W2p = (ushort_t*)(wsf + W2P_OFF);
    float* entP = wsf + ENT_OFF;
    float* cntP = wsf + CNT_OFF;

    k1_gather<<<(R_TOT + T_NT) / 2, 256, 0, stream>>>(inp_word, tgt_ids, W, x, wtgt);
    k1b_wtgtT4<<<64, 256, 0, stream>>>(wtgt, wtgtT4);
    k0_w2t<<<dim3(T_NT / 32, HH / 32), 256, 0, stream>>>(W2, W2Tf, W2p);
    k2_hdn<<<dim3(R_TOT / 64, HH / 64), 256, 0, stream>>>(x, W1, b1, hdn, hdnB);
    k3_fused<<<NBLK, 256, 0, stream>>>(hdnB, hdn, W2p, W2Tf, b2, gumbel,
                                       inp_word, keyword_table, tgt_ids, lut,
                                       x, wtgtT4, out, entP, cntP);
    k4_loss<<<1, 256, 0, stream>>>(entP, cntP, out);
}

// Round 12
// 199.472 us; speedup vs baseline: 3.7482x; 1.0335x over previous
//
#include <hip/hip_runtime.h>
#include <cstdint>

#define R_TOT 16384
#define T_NT  2048
#define DD    128
#define HH    512
#define MC_   20
#define BR    32             // rows per block in k3
#define STEPS 64             // 2048 / 32 cols
#define NBLK  (R_TOT / BR)   // 512

// Output layout (floats)
#define MASK_OFF 0
#define LOGP_OFF 16384
#define WORD_OFF 32768
#define CHAR_OFF 49152
#define EMB_OFF  376832          // 49152 + 16384*20
#define LOSS_OFF 2473984         // 376832 + 16384*128

// ws layout (float slots)
#define X_OFF     0              // x f32 [16384][128]
#define HDN_OFF   2097152        // hdn f32 [16384][512]
#define HDNB_OFF  10485760       // hdn bf16 ushort[16384*512]
#define WT_OFF    14680064       // wtgt f32 [2048][128]
#define WTT4_OFF  14942208       // wtgtT4 ushort[128][8][64][8]  (524288)
#define W2T_OFF   15204352       // W2Tf f32 [2048][512]
#define W2P_OFF   16252928       // W2p ushort[64][16][4][32][8]  (1048576)
#define ENT_OFF   16777216       // 512
#define CNT_OFF   16777728       // 512

typedef __attribute__((ext_vector_type(8))) short short8v;
typedef __attribute__((ext_vector_type(4))) float f32x4;
typedef unsigned short ushort_t;

__device__ __forceinline__ ushort_t f2bf(float f) {
    union { float f; unsigned int u; } v; v.f = f;
    unsigned int r = v.u + 0x7FFFu + ((v.u >> 16) & 1u);
    return (ushort_t)(r >> 16);
}

__device__ __forceinline__ void stage16(const ushort_t* gsrc, ushort_t* ldst) {
    __builtin_amdgcn_global_load_lds(
        (const __attribute__((address_space(1))) unsigned int*)gsrc,
        (__attribute__((address_space(3))) unsigned int*)ldst, 16, 0, 0);
}

// ---------------- K1: gather embeddings ----------------
__global__ __launch_bounds__(256) void k1_gather(
    const int* __restrict__ inp_word, const int* __restrict__ tgt_ids,
    const float* __restrict__ W, float* __restrict__ x, float* __restrict__ wtgt)
{
    int row = blockIdx.x * 2 + (threadIdx.x >> 7);
    int d = threadIdx.x & 127;
    if (row < R_TOT) {
        int wsrc = inp_word[row];
        x[(size_t)row * DD + d] = W[(size_t)wsrc * DD + d];
    } else {
        int rr = row - R_TOT;
        if (rr < T_NT) {
            int wsrc = tgt_ids[rr];
            wtgt[(size_t)rr * DD + d] = W[(size_t)wsrc * DD + d];
        }
    }
}

// ---------------- K1b: wtgt -> wtgtT4 PV B-fragment pack ----------------
// wtgtT4[((js*2+cs)*8+df)*512 + lane*8 + j] =
//   j<4 ? bf16(wtgt[js*32+cs*16+(lane>>4)*4+j][df*16+(lane&15)]) : 0
__global__ __launch_bounds__(256) void k1b_wtgtT4(
    const float* __restrict__ wtgt, ushort_t* __restrict__ wtgtT4)
{
    const int js = blockIdx.x, t = threadIdx.x;
    #pragma unroll
    for (int i = 0; i < 4; ++i) {
        int s = i * 256 + t;
        int cs = s >> 9, rem = s & 511;
        int df = rem >> 6, lane = rem & 63;
        int lrow = lane & 15, kg = lane >> 4;
        ushort_t* dst = wtgtT4 + (size_t)(((js * 2 + cs) * 8 + df) * 512 + lane * 8);
        #pragma unroll
        for (int j = 0; j < 8; ++j) {
            dst[j] = (j < 4)
                ? f2bf(wtgt[(size_t)(js * 32 + cs * 16 + kg * 4 + j) * DD + df * 16 + lrow])
                : (ushort_t)0;
        }
    }
}

// ---------------- K0: W2 [512][2048] -> W2Tf f32 + W2p fragment pack ----------------
// W2p chunk (js,ks): 1024 ushorts, kgrp-major: offset (kgrp*32+c)*8+i =
//   bf16(W2[ks*32+kgrp*8+i][js*32+c])  -> consuming lane reads lane-linear LDS.
__global__ __launch_bounds__(256) void k0_w2t(
    const float* __restrict__ W2, float* __restrict__ W2Tf, ushort_t* __restrict__ W2p)
{
    __shared__ float tile[32][33];
    const int js = blockIdx.x, ks = blockIdx.y;
    const int cb = js * 32, kb = ks * 32;
    const int lx = threadIdx.x & 31, ly = threadIdx.x >> 5;
    #pragma unroll
    for (int i = 0; i < 32; i += 8)
        tile[ly + i][lx] = W2[(size_t)(kb + ly + i) * T_NT + cb + lx];
    __syncthreads();
    #pragma unroll
    for (int i = 0; i < 32; i += 8) {
        int c = cb + ly + i, k = kb + lx;
        W2Tf[(size_t)c * HH + k] = tile[lx][ly + i];
    }
    if (threadIdx.x < 128) {
        int c = threadIdx.x >> 2, kgrp = threadIdx.x & 3;
        ushort_t* dst = W2p + (size_t)((js * 16 + ks) * 1024 + (kgrp * 32 + c) * 8);
        #pragma unroll
        for (int i = 0; i < 8; ++i)
            dst[i] = f2bf(tile[kgrp * 8 + i][c]);
    }
}

// ---------------- K2: hdn = relu(x @ W1 + b1), fp32 + bf16 outputs ----------------
__global__ __launch_bounds__(256) void k2_hdn(
    const float* __restrict__ x, const float* __restrict__ W1,
    const float* __restrict__ b1, float* __restrict__ hdn, ushort_t* __restrict__ hdnB)
{
    __shared__ float As[16][64];
    __shared__ float Bs[16][64];
    const int t = threadIdx.x;
    const int bm = blockIdx.x * 64;
    const int bn = blockIdx.y * 64;
    const int tx = t & 15, ty = t >> 4;
    float acc[4][4] = {};
    for (int k0 = 0; k0 < DD; k0 += 16) {
        {
            int m = t >> 2, kq = t & 3;
            float4 v = *(const float4*)(x + (size_t)(bm + m) * DD + k0 + kq * 4);
            As[kq * 4 + 0][m] = v.x; As[kq * 4 + 1][m] = v.y;
            As[kq * 4 + 2][m] = v.z; As[kq * 4 + 3][m] = v.w;
        }
        {
            int k = t >> 4, nq = t & 15;
            *(float4*)(&Bs[k][nq * 4]) =
                *(const float4*)(W1 + (size_t)(k0 + k) * HH + bn + nq * 4);
        }
        __syncthreads();
        #pragma unroll
        for (int k = 0; k < 16; ++k) {
            float a[4], b[4];
            #pragma unroll
            for (int i = 0; i < 4; i++) a[i] = As[k][ty * 4 + i];
            #pragma unroll
            for (int j = 0; j < 4; j++) b[j] = Bs[k][tx * 4 + j];
            #pragma unroll
            for (int i = 0; i < 4; i++)
                #pragma unroll
                for (int j = 0; j < 4; j++)
                    acc[i][j] = fmaf(a[i], b[j], acc[i][j]);
        }
        __syncthreads();
    }
    #pragma unroll
    for (int i = 0; i < 4; i++) {
        int m = bm + ty * 4 + i;
        int n = bn + tx * 4;
        float4 v;
        v.x = fmaxf(acc[i][0] + b1[n + 0], 0.f);
        v.y = fmaxf(acc[i][1] + b1[n + 1], 0.f);
        v.z = fmaxf(acc[i][2] + b1[n + 2], 0.f);
        v.w = fmaxf(acc[i][3] + b1[n + 3], 0.f);
        *(float4*)(hdn + (size_t)m * HH + n) = v;
        ushort4 hb;
        hb.x = f2bf(v.x); hb.y = f2bf(v.y); hb.z = f2bf(v.z); hb.w = f2bf(v.w);
        *(ushort4*)(hdnB + (size_t)m * HH + n) = hb;
    }
}

// ---------------- K3: swapped S-MFMA + 48KB ring staging (3 blocks/CU) ----------------
// 512 blocks x 32 rows, 4 waves = 2 Mgrp x 2 Cgrp. Three 16KB K-half buffers (ring);
// 2 barriers/step; each stage gets >=1/3-step drain cover. Lane-linear B ds_reads.
__global__ __launch_bounds__(256) void k3_fused(
    const ushort_t* __restrict__ hdnB, const float* __restrict__ hdn,
    const ushort_t* __restrict__ W2p, const float* __restrict__ W2Tf,
    const float* __restrict__ b2, const float* __restrict__ gumbel,
    const int* __restrict__ inp_word, const int* __restrict__ keyword_table,
    const int* __restrict__ tgt_ids, const int* __restrict__ lut,
    const float* __restrict__ x, const ushort_t* __restrict__ wtgtT4,
    float* __restrict__ out, float* __restrict__ entP, float* __restrict__ cntP)
{
    __shared__ ushort_t wS3[3 * 8192];      // 48 KB ring of 16KB K-half tiles; scratch later
    __shared__ float statC1[32 * 8];
    __shared__ int   candS[BR * 2];
    __shared__ float invs2S[BR], entS[BR];
    __shared__ int   mskS[BR];

    const int t = threadIdx.x;
    const int wid = t >> 6, lane = t & 63;
    const int Mgrp = wid >> 1, Cgrp = wid & 1;
    const int lrow = lane & 15, kgrp = lane >> 4;
    const int row0 = blockIdx.x * BR;
    const int rowA = row0 + Mgrp * 16 + lrow;

    // ---- hdn fragments (MFMA B operand after swap) ----
    short8v av[16];
    #pragma unroll
    for (int ks = 0; ks < 16; ++ks)
        av[ks] = *(const short8v*)(hdnB + (size_t)rowA * HH + ks * 32 + kgrp * 8);

    // ---- lane-linear LDS read offset (conflict-free) + stage offset ----
    const int rdoff = (kgrp * 32 + Cgrp * 16 + lrow) * 8;   // ushort units
    const int stoff = t * 8;

    // ---- per-lane pointers ----
    const float* gp = gumbel + (size_t)rowA * T_NT + Cgrp * 16 + kgrp * 4;
    const float* b2p = b2 + Cgrp * 16 + kgrp * 4;
    const ushort_t* vtp = wtgtT4 + (size_t)Cgrp * 4096 + lane * 8;

    // ---- scalar stats (per lane = per row-slice) ----
    float m_ = -1e30f, sE_ = 0.f, sEl_ = 0.f, s2_ = 0.f;
    float a1_ = -1e30f, a2_ = -1e30f;
    int i1_ = 0, i2_ = 0;
    f32x4 accpv[8];
    #pragma unroll
    for (int df = 0; df < 8; ++df) accpv[df] = (f32x4){0.f, 0.f, 0.f, 0.f};

    // ---- prologue: stage K-halves 0,1 into bufs 0,1; step-0 scalars ----
    {
        const ushort_t* sp = W2p + stoff;
        #pragma unroll
        for (int i = 0; i < 4; ++i) stage16(sp + i * 2048, wS3 + stoff + i * 2048);
        #pragma unroll
        for (int i = 0; i < 4; ++i) stage16(sp + 8192 + i * 2048, wS3 + 8192 + stoff + i * 2048);
    }
    float4 g4 = *(const float4*)gp;
    float4 b2v4 = *(const float4*)b2p;
    __syncthreads();   // halves 0,1 resident

    const ushort_t* spT = W2p + 16384 + stoff;   // next K-half to stage (t=2)
    int offC = 0, offN = 8192, offS = 16384;     // ring offsets (uniform)
    int c0 = Cgrp * 16 + kgrp * 4;

    for (int s = 0; s < STEPS; ++s) {
        // ---- half 0: consume buf offC (ks 0..7) ----
        f32x4 ac0 = (f32x4){0.f,0.f,0.f,0.f}, ac1 = ac0, ac2 = ac0, ac3 = ac0;
        {
            const ushort_t* cr = wS3 + offC + rdoff;
            #pragma unroll
            for (int ksl = 0; ksl < 8; ksl += 4) {
                ac0 = __builtin_amdgcn_mfma_f32_16x16x32_bf16(*(const short8v*)(cr + (ksl+0)*1024), av[ksl+0], ac0, 0, 0, 0);
                ac1 = __builtin_amdgcn_mfma_f32_16x16x32_bf16(*(const short8v*)(cr + (ksl+1)*1024), av[ksl+1], ac1, 0, 0, 0);
                ac2 = __builtin_amdgcn_mfma_f32_16x16x32_bf16(*(const short8v*)(cr + (ksl+2)*1024), av[ksl+2], ac2, 0, 0, 0);
                ac3 = __builtin_amdgcn_mfma_f32_16x16x32_bf16(*(const short8v*)(cr + (ksl+3)*1024), av[ksl+3], ac3, 0, 0, 0);
            }
        }
        __syncthreads();   // mid: buf(2s) free; stage(2s+1..) drained

        // ---- stage K-half 2s+2 into buf offS ----
        if (2 * s + 2 < 2 * STEPS) {
            ushort_t* dst = wS3 + offS + stoff;
            #pragma unroll
            for (int i = 0; i < 4; ++i) stage16(spT + i * 2048, dst + i * 2048);
            spT += 8192;
        }
        { int tmp = offC; offC = offN; offN = offS; offS = tmp; }

        // ---- long-cover loads: next-step scalars + this step's PV B-frags ----
        const int adv = (s + 1 < STEPS) ? 32 : 0;
        float4 gn4 = *(const float4*)(gp + adv);
        float4 b2n4 = *(const float4*)(b2p + adv);
        gp += 32; b2p += 32;
        short8v bvf[8];
        #pragma unroll
        for (int df = 0; df < 8; ++df)
            bvf[df] = *(const short8v*)(vtp + df * 512);
        vtp += 8192;

        // ---- half 1: consume buf offC (ks 8..15) ----
        {
            const ushort_t* cr = wS3 + offC + rdoff;
            #pragma unroll
            for (int ksl = 0; ksl < 8; ksl += 4) {
                ac0 = __builtin_amdgcn_mfma_f32_16x16x32_bf16(*(const short8v*)(cr + (ksl+0)*1024), av[8+ksl+0], ac0, 0, 0, 0);
                ac1 = __builtin_amdgcn_mfma_f32_16x16x32_bf16(*(const short8v*)(cr + (ksl+1)*1024), av[8+ksl+1], ac1, 0, 0, 0);
                ac2 = __builtin_amdgcn_mfma_f32_16x16x32_bf16(*(const short8v*)(cr + (ksl+2)*1024), av[8+ksl+2], ac2, 0, 0, 0);
                ac3 = __builtin_amdgcn_mfma_f32_16x16x32_bf16(*(const short8v*)(cr + (ksl+3)*1024), av[8+ksl+3], ac3, 0, 0, 0);
            }
        }
        f32x4 acc = (ac0 + ac1) + (ac2 + ac3);

        // ---- stats + top2 + in-register P -> pav ----
        short8v pav;
        pav[4] = 0; pav[5] = 0; pav[6] = 0; pav[7] = 0;
        #pragma unroll
        for (int q = 0; q < 4; ++q) {
            float l = acc[q] + b2v4[q];
            m_ = fmaxf(m_, l);
            float e1 = __expf(l);
            sE_ += e1; sEl_ = fmaf(e1, l, sEl_);
            float a = l + g4[q];
            float p = __expf(2.0f * a);
            s2_ += p;
            if (a > a1_) { a2_ = a1_; i2_ = i1_; a1_ = a; i1_ = c0 + q; }
            else if (a > a2_) { a2_ = a; i2_ = c0 + q; }
            pav[q] = (short)f2bf(p);
        }

        // ---- PV ----
        #pragma unroll
        for (int df = 0; df < 8; ++df)
            accpv[df] = __builtin_amdgcn_mfma_f32_16x16x32_bf16(pav, bvf[df], accpv[df], 0, 0, 0);

        g4 = gn4; b2v4 = b2n4; c0 += 32;
        __syncthreads();   // end: buf(2s+1) free; stage(2s+2) drained

        // ---- stage K-half 2s+3 into buf offS ----
        if (2 * s + 3 < 2 * STEPS) {
            ushort_t* dst = wS3 + offS + stoff;
            #pragma unroll
            for (int i = 0; i < 4; ++i) stage16(spT + i * 2048, dst + i * 2048);
            spT += 8192;
        }
        { int tmp = offC; offC = offN; offN = offS; offS = tmp; }
    }

    // ---- in-wave reduction across kgrp lanes ----
    #pragma unroll
    for (int mk = 16; mk < 64; mk <<= 1) {
        m_ = fmaxf(m_, __shfl_xor(m_, mk));
        sE_ += __shfl_xor(sE_, mk);
        sEl_ += __shfl_xor(sEl_, mk);
        s2_ += __shfl_xor(s2_, mk);
        float ob1 = __shfl_xor(a1_, mk); int oj1 = __shfl_xor(i1_, mk);
        float ob2 = __shfl_xor(a2_, mk); int oj2 = __shfl_xor(i2_, mk);
        if (ob1 > a1_ || (ob1 == a1_ && oj1 < i1_)) {
            if (a1_ > ob2 || (a1_ == ob2 && i1_ < oj2)) { a2_ = a1_; i2_ = i1_; }
            else { a2_ = ob2; i2_ = oj2; }
            a1_ = ob1; i1_ = oj1;
        } else {
            if (ob1 > a2_) { a2_ = ob1; i2_ = oj1; }
        }
    }

    // ---- phase 1: Cgrp1 publishes stats + PV partials ----
    if (Cgrp == 1 && lane < 16) {
        float* st = &statC1[(Mgrp * 16 + lane) * 8];
        st[0] = m_; st[1] = sE_; st[2] = sEl_; st[3] = s2_;
        st[4] = a1_; st[5] = __int_as_float(i1_);
        st[6] = a2_; st[7] = __int_as_float(i2_);
    }
    float* scr = (float*)wS3;   // scratch: [Mgrp][16 rows][128 d]
    if (Cgrp == 1) {
        #pragma unroll
        for (int df = 0; df < 8; ++df)
            #pragma unroll
            for (int q = 0; q < 4; ++q)
                scr[Mgrp * 2048 + (kgrp * 4 + q) * 128 + df * 16 + lrow] = accpv[df][q];
    }
    __syncthreads();

    // ---- phase 2: Cgrp0 merges ----
    if (Cgrp == 0) {
        if (lane < 16) {
            const float* st = &statC1[(Mgrp * 16 + lane) * 8];
            float bm = st[0], bsE = st[1], bsEl = st[2], bs2 = st[3];
            float ob1 = st[4]; int oj1 = __float_as_int(st[5]);
            float ob2 = st[6]; int oj2 = __float_as_int(st[7]);
            float m = fmaxf(m_, bm);
            float sE = sE_ + bsE, sEl = sEl_ + bsEl, s2 = s2_ + bs2;
            float a1 = a1_, a2 = a2_; int i1 = i1_, i2 = i2_;
            if (ob1 > a1 || (ob1 == a1 && oj1 < i1)) {
                if (a1 > ob2 || (a1 == ob2 && i1 < oj2)) { a2 = a1; i2 = i1; }
                else { a2 = ob2; i2 = oj2; }
                a1 = ob1; i1 = oj1;
            } else {
                if (ob1 > a2) { a2 = ob1; i2 = oj1; }
            }
            int rl = Mgrp * 16 + lane;
            int grow = row0 + rl;
            int w_in = inp_word[grow];
            int msk = keyword_table[w_in] != 0;
            out[MASK_OFF + grow] = msk ? 1.0f : 0.0f;
            out[LOGP_OFF + grow] = msk ? m : 0.0f;
            invs2S[rl] = 1.0f / s2;
            mskS[rl] = msk;
            entS[rl] = msk ? (__logf(sE) - sEl / sE) : 0.0f;
            candS[rl * 2 + 0] = i1;
            candS[rl * 2 + 1] = i2;
        }
        #pragma unroll
        for (int df = 0; df < 8; ++df)
            #pragma unroll
            for (int q = 0; q < 4; ++q)
                accpv[df][q] += scr[Mgrp * 2048 + (kgrp * 4 + q) * 128 + df * 16 + lrow];
    }
    __syncthreads();

    // ---- x_emb store (Cgrp0 waves, full d) ----
    if (Cgrp == 0) {
        #pragma unroll
        for (int df = 0; df < 8; ++df) {
            #pragma unroll
            for (int q = 0; q < 4; ++q) {
                int rl = Mgrp * 16 + kgrp * 4 + q;
                int grow = row0 + rl;
                int d = df * 16 + lrow;
                float val = accpv[df][q] * invs2S[rl];
                if (!mskS[rl]) val = x[(size_t)grow * DD + d];
                out[EMB_OFF + (size_t)grow * DD + d] = val;
            }
        }
    }

    // ---- repair + word/char outputs: wave wid handles rows wid, wid+4, ... ----
    for (int rr = wid; rr < BR; rr += 4) {
        int grow = row0 + rr;
        int i1 = candS[rr * 2 + 0], i2 = candS[rr * 2 + 1];
        const float* hrow = hdn + (size_t)grow * HH;
        float4 h0 = *(const float4*)(hrow + lane * 8);
        float4 h1 = *(const float4*)(hrow + lane * 8 + 4);
        float v1, v2;
        {
            const float* wrow = W2Tf + (size_t)i1 * HH;
            float4 w0 = *(const float4*)(wrow + lane * 8);
            float4 w1 = *(const float4*)(wrow + lane * 8 + 4);
            float sdot = h0.x*w0.x + h0.y*w0.y + h0.z*w0.z + h0.w*w0.w
                       + h1.x*w1.x + h1.y*w1.y + h1.z*w1.z + h1.w*w1.w;
            #pragma unroll
            for (int mk = 1; mk < 64; mk <<= 1) sdot += __shfl_xor(sdot, mk);
            v1 = sdot + b2[i1] + gumbel[(size_t)grow * T_NT + i1];
        }
        {
            const float* wrow = W2Tf + (size_t)i2 * HH;
            float4 w0 = *(const float4*)(wrow + lane * 8);
            float4 w1 = *(const float4*)(wrow + lane * 8 + 4);
            float sdot = h0.x*w0.x + h0.y*w0.y + h0.z*w0.z + h0.w*w0.w
                       + h1.x*w1.x + h1.y*w1.y + h1.z*w1.z + h1.w*w1.w;
            #pragma unroll
            for (int mk = 1; mk < 64; mk <<= 1) sdot += __shfl_xor(sdot, mk);
            v2 = sdot + b2[i2] + gumbel[(size_t)grow * T_NT + i2];
        }
        int ibest = (v2 > v1 || (v2 == v1 && i2 < i1)) ? i2 : i1;
        int w_in = inp_word[grow];
        int msk = mskS[rr];
        int word = msk ? tgt_ids[ibest] : w_in;
        if (lane == 0) out[WORD_OFF + grow] = (float)word;
        if (lane < MC_)
            out[CHAR_OFF + (size_t)grow * MC_ + lane] = (float)lut[(size_t)word * MC_ + lane];
    }

    if (t == 0) {
        float es = 0.f; int cs = 0;
        #pragma unroll
        for (int r = 0; r < BR; r++) { es += entS[r]; cs += mskS[r]; }
        entP[blockIdx.x] = es;
        cntP[blockIdx.x] = (float)cs;
    }
}

// ---------------- K4: final loss reduction ----------------
__global__ __launch_bounds__(256) void k4_loss(
    const float* __restrict__ entP, const float* __restrict__ cntP, float* __restrict__ out)
{
    __shared__ float sE[256], sC[256];
    int t = threadIdx.x;
    float e = 0.f, c = 0.f;
    for (int i = t; i < NBLK; i += 256) { e += entP[i]; c += cntP[i]; }
    sE[t] = e; sC[t] = c;
    __syncthreads();
    for (int s = 128; s > 0; s >>= 1) {
        if (t < s) { sE[t] += sE[t + s]; sC[t] += sC[t + s]; }
        __syncthreads();
    }
    if (t == 0) {
        float ns = fmaxf(sC[0], 1.0f);
        out[LOSS_OFF] = 0.03f * sE[0] / ns;
    }
}

// ---------------- launch ----------------
extern "C" void kernel_launch(void* const* d_in, const int* in_sizes, int n_in,
                              void* d_out, int out_size, void* d_ws, size_t ws_size,
                              hipStream_t stream) {
    const int* inp_word = (const int*)d_in[0];
    const int* keyword_table = (const int*)d_in[3];
    const int* tgt_ids = (const int*)d_in[4];
    const int* lut = (const int*)d_in[5];
    const float* gumbel = (const float*)d_in[6];
    const float* W = (const float*)d_in[7];
    const float* W1 = (const float*)d_in[8];
    const float* b1 = (const float*)d_in[9];
    const float* W2 = (const float*)d_in[10];
    const float* b2 = (const float*)d_in[11];
    float* out = (float*)d_out;

    float* wsf = (float*)d_ws;
    float* x = wsf + X_OFF;
    float* hdn = wsf + HDN_OFF;
    ushort_t* hdnB = (ushort_t*)(wsf + HDNB_OFF);
    float* wtgt = wsf + WT_OFF;
    ushort_t* wtgtT4 = (ushort_t*)(wsf + WTT4_OFF);
    float* W2Tf = wsf + W2T_OFF;
    ushort_t* W2p = (ushort_t*)(wsf + W2P_OFF);
    float* entP = wsf + ENT_OFF;
    float* cntP = wsf + CNT_OFF;

    k1_gather<<<(R_TOT + T_NT) / 2, 256, 0, stream>>>(inp_word, tgt_ids, W, x, wtgt);
    k1b_wtgtT4<<<64, 256, 0, stream>>>(wtgt, wtgtT4);
    k0_w2t<<<dim3(T_NT / 32, HH / 32), 256, 0, stream>>>(W2, W2Tf, W2p);
    k2_hdn<<<dim3(R_TOT / 64, HH / 64), 256, 0, stream>>>(x, W1, b1, hdn, hdnB);
    k3_fused<<<NBLK, 256, 0, stream>>>(hdnB, hdn, W2p, W2Tf, b2, gumbel,
                                       inp_word, keyword_table, tgt_ids, lut,
                                       x, wtgtT4, out, entP, cntP);
    k4_loss<<<1, 256, 0, stream>>>(entP, cntP, out);
}